// Round 2
// baseline (753.486 us; speedup 1.0000x reference)
//
#include <hip/hip_runtime.h>

// CRF forward (log partition), B=256, T=2048, N=64, MI355X.
//
// Round 9: fine-grained chunks (kC=32, 64 steps) -> 8192 independent scan
// chains (4 waves each), so every SIMD holds ~8 independent MFMA feedback
// chains and chain latency is hidden by chain-level parallelism instead of
// (absent) intra-chain ILP. Total MFMA count is unchanged (tree widens, not
// deepens). r7/r8 evidence: both ~27% occupancy and ~25-32% MfmaUtil at
// kC=8 regardless of LDS/barrier structure => serial-chain x low effective
// concurrency was binding, and kC=8 only has 2048 chains total.
//  - e streamed from global, 2-deep register pipeline (r8 machinery).
//  - s_setprio(1) around the MFMA cluster (free-running waves regime).
//  - Scratch tiers: kC=32 f32 (134 MB) > kC=16 (67 MB) > kC=8 (34 MB) >
//    bf16 in-place fallback; combine kernel templated on kC.

typedef __attribute__((ext_vector_type(4))) float f32x4;
typedef __attribute__((ext_vector_type(8))) short bf16x8;

namespace {
constexpr int kB = 256;
constexpr int kT = 2048;
constexpr int kN = 64;
constexpr int kStart = 1;  // GO
constexpr int kEnd = 2;    // EOS
constexpr long tileFloats(int C) { return (long)kB * C * 4 * 1024; }
constexpr long numTiles(int C) { return (long)kB * C * 4; }
}  // namespace

// ---------- pre-pass A (in-place): f32 row swizzle + exp ----------
// buf rows of 64 f32; within each row: out[pi(j)] = exp(in[j]),
// pi = ((j>>2)&3)*16 + ((j>>4)<<2) + (j&3). Row handled entirely within one
// wave (32 threads x 2 elems); loads complete before stores (lockstep).
__global__ void exp_swizzle_f32(float* buf) {
  const int total = kB * kT * 32;  // pairs
  int p = blockIdx.x * blockDim.x + threadIdx.x;
  const int stride = gridDim.x * blockDim.x;
  for (; p < total; p += stride) {
    const int r = p >> 5;
    const int j0 = (p & 31) << 1;
    float* row = buf + (size_t)r * kN;
    const float2 v = *(const float2*)(row + j0);
    const int pi = ((j0 >> 2) & 3) * 16 + ((j0 >> 4) << 2) + (j0 & 3);
    float2 o;
    o.x = __expf(v.x);
    o.y = __expf(v.y);
    *(float2*)(row + pi) = o;
  }
}

// ---------- pre-pass A' (no-clobber): f32 swizzle + exp into workspace ----
__global__ void exp_swizzle_f32_out(const float* __restrict__ in,
                                    float* __restrict__ out) {
  const int total = kB * kT * 32;  // pairs
  int p = blockIdx.x * blockDim.x + threadIdx.x;
  const int stride = gridDim.x * blockDim.x;
  for (; p < total; p += stride) {
    const int r = p >> 5;
    const int j0 = (p & 31) << 1;
    const float2 v = *(const float2*)(in + (size_t)r * kN + j0);
    const int pi = ((j0 >> 2) & 3) * 16 + ((j0 >> 4) << 2) + (j0 & 3);
    float2 o;
    o.x = __expf(v.x);
    o.y = __expf(v.y);
    *(float2*)(out + (size_t)r * kN + pi) = o;
  }
}

// ---------- pre-pass B (fallback): bf16 packed into lower 128 B of rows ----
__global__ void exp_swizzle_bf16(const float* in, char* outbase) {
  const int total = kB * kT * 32;  // pairs
  int p = blockIdx.x * blockDim.x + threadIdx.x;
  const int stride = gridDim.x * blockDim.x;
  for (; p < total; p += stride) {
    const int r = p >> 5;
    const int j0 = (p & 31) << 1;
    const float2 v = *(const float2*)(in + (size_t)r * kN + j0);
    const float e0 = __expf(v.x), e1 = __expf(v.y);
    unsigned u0 = __float_as_uint(e0);
    u0 += 0x7FFFu + ((u0 >> 16) & 1u);  // RNE to bf16
    unsigned u1 = __float_as_uint(e1);
    u1 += 0x7FFFu + ((u1 >> 16) & 1u);
    const unsigned d = (u1 & 0xFFFF0000u) | (u0 >> 16);
    const int pi = ((j0 >> 2) & 3) * 16 + ((j0 >> 4) << 2) + (j0 & 3);
    *(unsigned*)(outbase + (size_t)r * 256 + pi * 2) = d;
  }
}

// ---------- helpers ----------
__device__ __forceinline__ unsigned pack2bf(float lo, float hi) {
  return __builtin_amdgcn_perm(__float_as_uint(hi), __float_as_uint(lo), 0x07060302u);
}

__device__ __forceinline__ f32x4 expand2(unsigned u, unsigned v) {
  f32x4 e;
  e.x = __uint_as_float(u << 16);
  e.y = __uint_as_float(u & 0xFFFF0000u);
  e.z = __uint_as_float(v << 16);
  e.w = __uint_as_float(v & 0xFFFF0000u);
  return e;
}

// Per-step e-row fragment held in registers (2-deep pipeline).
template <bool F32>
struct ERow;
template <>
struct ERow<true> {
  f32x4 e0, e1, e2, e3;
};
template <>
struct ERow<false> {
  uint4 u0, u1;
};

template <bool F32>
__device__ __forceinline__ void load_erow(const char* p, ERow<F32>& r) {
  if constexpr (F32) {
    r.e0 = *(const f32x4*)(p + 0);
    r.e1 = *(const f32x4*)(p + 16);
    r.e2 = *(const f32x4*)(p + 32);
    r.e3 = *(const f32x4*)(p + 48);
  } else {
    r.u0 = *(const uint4*)(p + 0);
    r.u1 = *(const uint4*)(p + 16);
  }
}

// One step: Q = E*Acc (8 MFMA), Acc' = Q .* e. e comes from registers.
template <bool F32>
__device__ __forceinline__ void step_reg(f32x4 (&ps)[4], const bf16x8 (&af)[4][2],
                                         const ERow<F32>& r) {
  f32x4 e0, e1, e2, e3;
  if constexpr (F32) {
    e0 = r.e0;
    e1 = r.e1;
    e2 = r.e2;
    e3 = r.e3;
  } else {
    e0 = expand2(r.u0.x, r.u0.y);
    e1 = expand2(r.u0.z, r.u0.w);
    e2 = expand2(r.u1.x, r.u1.y);
    e3 = expand2(r.u1.z, r.u1.w);
  }

  union { unsigned u[4]; bf16x8 s; } b0u, b1u;
  b0u.u[0] = pack2bf(ps[0].x, ps[0].y);
  b0u.u[1] = pack2bf(ps[0].z, ps[0].w);
  b0u.u[2] = pack2bf(ps[1].x, ps[1].y);
  b0u.u[3] = pack2bf(ps[1].z, ps[1].w);
  const bf16x8 b0 = b0u.s;
  b1u.u[0] = pack2bf(ps[2].x, ps[2].y);
  b1u.u[1] = pack2bf(ps[2].z, ps[2].w);
  b1u.u[2] = pack2bf(ps[3].x, ps[3].y);
  b1u.u[3] = pack2bf(ps[3].z, ps[3].w);
  const bf16x8 b1 = b1u.s;

  const f32x4 z4 = {0.f, 0.f, 0.f, 0.f};
  __builtin_amdgcn_s_setprio(1);
  f32x4 q0 = __builtin_amdgcn_mfma_f32_16x16x32_bf16(af[0][0], b0, z4, 0, 0, 0);
  f32x4 q1 = __builtin_amdgcn_mfma_f32_16x16x32_bf16(af[1][0], b0, z4, 0, 0, 0);
  f32x4 q2 = __builtin_amdgcn_mfma_f32_16x16x32_bf16(af[2][0], b0, z4, 0, 0, 0);
  f32x4 q3 = __builtin_amdgcn_mfma_f32_16x16x32_bf16(af[3][0], b0, z4, 0, 0, 0);
  q0 = __builtin_amdgcn_mfma_f32_16x16x32_bf16(af[0][1], b1, q0, 0, 0, 0);
  q1 = __builtin_amdgcn_mfma_f32_16x16x32_bf16(af[1][1], b1, q1, 0, 0, 0);
  q2 = __builtin_amdgcn_mfma_f32_16x16x32_bf16(af[2][1], b1, q2, 0, 0, 0);
  q3 = __builtin_amdgcn_mfma_f32_16x16x32_bf16(af[3][1], b1, q3, 0, 0, 0);
  __builtin_amdgcn_s_setprio(0);

  ps[0] = q0 * e0;
  ps[1] = q1 * e1;
  ps[2] = q2 * e2;
  ps[3] = q3 * e3;
}

// Per-wave renorm by exact power of 2 from lane 0's ps[0].x exponent.
// Spread bounded (~2^21); 4-step growth <= 2^56 -> max < 2^78, safe.
__device__ __forceinline__ void renorm(f32x4 (&ps)[4], float& tot_e) {
  const unsigned eref = __builtin_amdgcn_readfirstlane(__float_as_uint(ps[0].x));
  const int e = (int)((eref >> 23) & 0xFFu) - 127;
  const float sc = __uint_as_float((unsigned)(127 - e) << 23);
#pragma unroll
  for (int mt = 0; mt < 4; ++mt) ps[mt] *= sc;
  tot_e += (float)e;
}

__device__ __forceinline__ float exp2i(int d) {  // 2^d for d in [-126, 127]
  return (d <= -127) ? 0.f : __uint_as_float((unsigned)(127 + d) << 23);
}

// ---------- chunk kernel: 256 threads = 1 chunk x 4 waves, no LDS ----------
template <bool F32, int C>
__global__ __launch_bounds__(256, 4) void chunk_kernel(
    const char* __restrict__ eu, const float* __restrict__ trans,
    const int* __restrict__ lengths, char* __restrict__ scr, int scrStride) {
  constexpr int kL = kT / C;  // steps per chunk
  const int b = blockIdx.x / C;
  const int c = blockIdx.x % C;
  const int len = lengths[b];
  const int start = c * kL;
  int steps = len - start;
  if (steps <= 0) return;  // inactive chunk (block-uniform early exit)
  if (steps > kL) steps = kL;

  const int t8 = threadIdx.x;
  const int lane = t8 & 63;
  const int w = t8 >> 6;
  const int col = lane & 15;
  const int q4 = lane >> 4;

  // Static A-fragments, psi-permuted K (verified rounds 2-8).
  bf16x8 af[4][2];
#pragma unroll
  for (int mt = 0; mt < 4; ++mt) {
#pragma unroll
    for (int kc = 0; kc < 2; ++kc) {
      union { unsigned u[4]; bf16x8 s; } fr;
#pragma unroll
      for (int jp = 0; jp < 4; ++jp) {
        const int j0 = 2 * jp, j1 = 2 * jp + 1;
        const int k0 = (2 * kc + (j0 >> 2)) * 16 + q4 * 4 + (j0 & 3);
        const int k1 = (2 * kc + (j1 >> 2)) * 16 + q4 * 4 + (j1 & 3);
        unsigned e0 = __float_as_uint(__expf(trans[(mt * 16 + col) * kN + k0])) + 0x8000u;
        unsigned e1 = __float_as_uint(__expf(trans[(mt * 16 + col) * kN + k1])) + 0x8000u;
        fr.u[jp] = __builtin_amdgcn_perm(e1, e0, 0x07060302u);
      }
      af[mt][kc] = fr.s;
    }
  }

  // Acc = identity columns; this wave owns columns w*16..w*16+15.
  const int mycol = w * 16 + col;
  f32x4 ps[4];
#pragma unroll
  for (int mt = 0; mt < 4; ++mt) {
    const int rb = mt * 16 + q4 * 4;
    f32x4 v;
    v.x = (rb + 0 == mycol) ? 1.f : 0.f;
    v.y = (rb + 1 == mycol) ? 1.f : 0.f;
    v.z = (rb + 2 == mycol) ? 1.f : 0.f;
    v.w = (rb + 3 == mycol) ? 1.f : 0.f;
    ps[mt] = v;
  }

  // e-rows: 256-B stride; this lane's q4 segment (swizzled layout from
  // pre-pass). F32: 64 B at q4*64; bf16: 32 B at q4*32. 16-lane broadcast
  // addresses coalesce; 4 waves share the row via L1.
  const char* gq = eu + (size_t)(b * kT + start) * 256 + q4 * (F32 ? 64 : 32);

  ERow<F32> EA, EB;
  load_erow<F32>(gq, EA);
  load_erow<F32>(gq + (steps > 1 ? 256 : 0), EB);

  float tot_e = 0.0f;
  int i = 0;
  // Main loop: 8 steps/iter, 2-deep software pipeline, renorm every 4 steps.
  // All prefetch rows i+2..i+9 are in-bounds under the i+10<=steps guard.
  for (; i + 10 <= steps; i += 8) {
    const char* g = gq + (size_t)i * 256;
    step_reg<F32>(ps, af, EA); load_erow<F32>(g + 2 * 256, EA);
    step_reg<F32>(ps, af, EB); load_erow<F32>(g + 3 * 256, EB);
    step_reg<F32>(ps, af, EA); load_erow<F32>(g + 4 * 256, EA);
    step_reg<F32>(ps, af, EB); load_erow<F32>(g + 5 * 256, EB);
    renorm(ps, tot_e);
    step_reg<F32>(ps, af, EA); load_erow<F32>(g + 6 * 256, EA);
    step_reg<F32>(ps, af, EB); load_erow<F32>(g + 7 * 256, EB);
    step_reg<F32>(ps, af, EA); load_erow<F32>(g + 8 * 256, EA);
    step_reg<F32>(ps, af, EB); load_erow<F32>(g + 9 * 256, EB);
    renorm(ps, tot_e);
  }
  // Tail (< 10 steps): clamped prefetch keeps all loads in-bounds.
  for (; i < steps; ++i) {
    step_reg<F32>(ps, af, EA);
    EA = EB;
    const int nx = (i + 2 < steps) ? (i + 2) : (steps - 1);
    load_erow<F32>(gq + (size_t)nx * 256, EB);
    if ((i & 3) == 3) renorm(ps, tot_e);
  }

  // Store 64x16 tile, column-major flat index F = tile*1024 + col*64 + row,
  // mapped to scratch slots of 32 floats with byte stride scrStride.
  const long tileIdx = ((long)b * C + c) * 4 + w;
#pragma unroll
  for (int mt = 0; mt < 4; ++mt) {
    const long slot = tileIdx * 32 + col * 2 + (mt >> 1);
    char* addr = scr + slot * (long)scrStride + ((mt & 1) * 16 + q4 * 4) * 4;
    *(f32x4*)addr = ps[mt];
  }
  if (lane == 0) {
    const long F = tileFloats(C) + tileIdx;
    *(float*)(scr + (F >> 5) * (long)scrStride + (F & 31) * 4) = tot_e;
  }
}

// ---------- combine: per batch, chain the chunk matrices (one wave) ----------
template <int C>
__global__ __launch_bounds__(64) void combine_kernel(
    const char* __restrict__ scr, int scrStride, const float* __restrict__ trans,
    const int* __restrict__ lengths, float* __restrict__ out) {
  constexpr int kL = kT / C;
  const int b = blockIdx.x;
  const int j = threadIdx.x;
  const int len = lengths[b];

#define LDS_SCR(F) (*(const float*)(scr + ((long)(F) >> 5) * (long)scrStride + ((F) & 31) * 4))

  // alpha after chunk 0 = column kStart of chunk-0 matrix (wave 0's tile).
  const long t0 = (long)b * C * 4;
  float a = LDS_SCR(t0 * 1024 + kStart * 64 + j);
  float totE = LDS_SCR(tileFloats(C) + t0);

  for (int c = 1; c < C; ++c) {
    if (c * kL >= len) break;  // chunks are contiguous-active
    const long tb = ((long)b * C + c) * 4;
    float s0 = 0.f, s1 = 0.f, s2 = 0.f, s3 = 0.f;
#pragma unroll
    for (int k16 = 0; k16 < 16; ++k16) {
      const float a0 = __int_as_float(__builtin_amdgcn_readlane(__float_as_int(a), k16));
      const float a1 = __int_as_float(__builtin_amdgcn_readlane(__float_as_int(a), 16 + k16));
      const float a2 = __int_as_float(__builtin_amdgcn_readlane(__float_as_int(a), 32 + k16));
      const float a3 = __int_as_float(__builtin_amdgcn_readlane(__float_as_int(a), 48 + k16));
      s0 = fmaf(LDS_SCR((tb + 0) * 1024 + k16 * 64 + j), a0, s0);
      s1 = fmaf(LDS_SCR((tb + 1) * 1024 + k16 * 64 + j), a1, s1);
      s2 = fmaf(LDS_SCR((tb + 2) * 1024 + k16 * 64 + j), a2, s2);
      s3 = fmaf(LDS_SCR((tb + 3) * 1024 + k16 * 64 + j), a3, s3);
    }
    const float e0 = LDS_SCR(tileFloats(C) + tb + 0);
    const float e1 = LDS_SCR(tileFloats(C) + tb + 1);
    const float e2 = LDS_SCR(tileFloats(C) + tb + 2);
    const float e3 = LDS_SCR(tileFloats(C) + tb + 3);
    const float em = fmaxf(fmaxf(e0, e1), fmaxf(e2, e3));
    a = s0 * exp2i((int)(e0 - em)) + s1 * exp2i((int)(e1 - em)) +
        s2 * exp2i((int)(e2 - em)) + s3 * exp2i((int)(e3 - em));
    totE += em;

    // renorm alpha (exact power of 2 from the wave max)
    float m = a;
#pragma unroll
    for (int mask = 1; mask < 64; mask <<= 1) m = fmaxf(m, __shfl_xor(m, mask));
    const int e = (int)((__float_as_uint(m) >> 23) & 0xFFu) - 127;
    a *= exp2i(-e);
    totE += (float)e;
  }

  float term = a * __expf(trans[kEnd * kN + j]);
#pragma unroll
  for (int mask = 1; mask < 64; mask <<= 1) term += __shfl_xor(term, mask);

  if (j == 0) out[b] = totE * 0.69314718055994530942f + logf(term);
#undef LDS_SCR
}

extern "C" void kernel_launch(void* const* d_in, const int* in_sizes, int n_in,
                              void* d_out, int out_size, void* d_ws, size_t ws_size,
                              hipStream_t stream) {
  const float* unary = (const float*)d_in[0];  // [B, T, N] fp32, 128 MiB
  const float* trans = (const float*)d_in[1];  // [N, N] fp32
  const int* lengths = (const int*)d_in[2];    // [B] int32
  float* out = (float*)d_out;                  // [B] fp32

  const size_t euBytes = (size_t)kB * kT * 256;  // 128 MiB
  const size_t scr32 = (size_t)(tileFloats(32) + numTiles(32)) * 4;  // ~134 MB
  const size_t scr16 = (size_t)(tileFloats(16) + numTiles(16)) * 4;  // ~67 MB
  const size_t scr8 = (size_t)(tileFloats(8) + numTiles(8)) * 4;     // ~34 MB

  if (ws_size >= euBytes + scr32) {
    // No-clobber: exp table in workspace; d_in[0] untouched. kC=32.
    exp_swizzle_f32_out<<<dim3(4096), dim3(256), 0, stream>>>(unary, (float*)d_ws);
    chunk_kernel<true, 32><<<dim3(kB * 32), dim3(256), 0, stream>>>(
        (const char*)d_ws, trans, lengths, (char*)d_ws + euBytes, 128);
    combine_kernel<32><<<dim3(kB), dim3(64), 0, stream>>>(
        (const char*)d_ws + euBytes, 128, trans, lengths, out);
  } else if (ws_size >= scr32) {
    // In-place table; tiles in workspace. kC=32.
    exp_swizzle_f32<<<dim3(4096), dim3(256), 0, stream>>>((float*)d_in[0]);
    chunk_kernel<true, 32><<<dim3(kB * 32), dim3(256), 0, stream>>>(
        (const char*)d_in[0], trans, lengths, (char*)d_ws, 128);
    combine_kernel<32><<<dim3(kB), dim3(64), 0, stream>>>((char*)d_ws, 128,
                                                          trans, lengths, out);
  } else if (ws_size >= scr16) {
    // kC=16 tier.
    exp_swizzle_f32<<<dim3(4096), dim3(256), 0, stream>>>((float*)d_in[0]);
    chunk_kernel<true, 16><<<dim3(kB * 16), dim3(256), 0, stream>>>(
        (const char*)d_in[0], trans, lengths, (char*)d_ws, 128);
    combine_kernel<16><<<dim3(kB), dim3(64), 0, stream>>>((char*)d_ws, 128,
                                                          trans, lengths, out);
  } else if (ws_size >= scr8) {
    // kC=8 tier (r8 structure).
    exp_swizzle_f32<<<dim3(4096), dim3(256), 0, stream>>>((float*)d_in[0]);
    chunk_kernel<true, 8><<<dim3(kB * 8), dim3(256), 0, stream>>>(
        (const char*)d_in[0], trans, lengths, (char*)d_ws, 128);
    combine_kernel<8><<<dim3(kB), dim3(64), 0, stream>>>((char*)d_ws, 128,
                                                         trans, lengths, out);
  } else {
    // Fallback: bf16 eu in lower 128 B of each 256-B row of d_in[0]; tiles
    // in the upper 128 B halves (byte-disjoint; harness restores inputs).
    exp_swizzle_bf16<<<dim3(4096), dim3(256), 0, stream>>>(unary, (char*)d_in[0]);
    chunk_kernel<false, 8><<<dim3(kB * 8), dim3(256), 0, stream>>>(
        (const char*)d_in[0], trans, lengths, (char*)d_in[0] + 128, 256);
    combine_kernel<8><<<dim3(kB), dim3(64), 0, stream>>>((const char*)d_in[0] + 128,
                                                         256, trans, lengths, out);
  }
}

// Round 3
// 495.479 us; speedup vs baseline: 1.5207x; 1.5207x over previous
//
#include <hip/hip_runtime.h>

// CRF forward (log partition), B=256, T=2048, N=64, MI355X.
//
// Round 10: dual-chain waves on the r7 substrate.
// Post-mortem r8/r9: ~2 waves/SIMD resident and ~25% MfmaUtil are invariant
// to chain count / LDS-vs-global / grid shape => the binding constraint is
// matrix work per resident wave-slot (per-SIMD MFMA throughput cost is
// ~19.4 cy for 16x16x32; pipe floor ~100us; each wave exposes only ~155 cy
// of MFMA per ~650 cy serial step). Fix: each wave carries TWO independent
// scan chains (chunk pair A,B of the same batch), interleaved step-pairs ->
// 2x matrix work per wave-slot at equal resident waves.
//  - Substrate = r7 (fastest measured: LDS staging, kC=8, barrier cadence).
//  - Block 256 thr = 4 waves, handles chunks (2cp, 2cp+1); wave owns 16
//    full columns of BOTH chunks. Grid = B*4 = 1024.
//  - combine back to C=8 (r9's C=32 combine was a ~300us serial regression).
//  - __launch_bounds__(256,3): ~168-reg budget, no spill risk for the
//    ~130-reg live set (af 32 + psA/psB 32 + staging 16 + transients).

typedef __attribute__((ext_vector_type(4))) float f32x4;
typedef __attribute__((ext_vector_type(8))) short bf16x8;

namespace {
constexpr int kB = 256;
constexpr int kT = 2048;
constexpr int kN = 64;
constexpr int kC = 8;        // chunks per sequence
constexpr int kL = kT / kC;  // 256 steps per chunk
constexpr int kStart = 1;    // GO
constexpr int kEnd = 2;      // EOS
constexpr long kTileFloats = (long)kB * kC * 4 * 1024;  // 8192 tiles x 64x16
constexpr long kNumTiles = (long)kB * kC * 4;
}  // namespace

// ---------- pre-pass A (in-place): f32 row swizzle + exp ----------
// buf rows of 64 f32; within each row: out[pi(j)] = exp(in[j]),
// pi = ((j>>2)&3)*16 + ((j>>4)<<2) + (j&3). Row handled entirely within one
// wave (32 threads x 2 elems); loads complete before stores (lockstep).
__global__ void exp_swizzle_f32(float* buf) {
  const int total = kB * kT * 32;  // pairs
  int p = blockIdx.x * blockDim.x + threadIdx.x;
  const int stride = gridDim.x * blockDim.x;
  for (; p < total; p += stride) {
    const int r = p >> 5;
    const int j0 = (p & 31) << 1;
    float* row = buf + (size_t)r * kN;
    const float2 v = *(const float2*)(row + j0);
    const int pi = ((j0 >> 2) & 3) * 16 + ((j0 >> 4) << 2) + (j0 & 3);
    float2 o;
    o.x = __expf(v.x);
    o.y = __expf(v.y);
    *(float2*)(row + pi) = o;
  }
}

// ---------- pre-pass A' (no-clobber): f32 swizzle + exp into workspace ----
__global__ void exp_swizzle_f32_out(const float* __restrict__ in,
                                    float* __restrict__ out) {
  const int total = kB * kT * 32;  // pairs
  int p = blockIdx.x * blockDim.x + threadIdx.x;
  const int stride = gridDim.x * blockDim.x;
  for (; p < total; p += stride) {
    const int r = p >> 5;
    const int j0 = (p & 31) << 1;
    const float2 v = *(const float2*)(in + (size_t)r * kN + j0);
    const int pi = ((j0 >> 2) & 3) * 16 + ((j0 >> 4) << 2) + (j0 & 3);
    float2 o;
    o.x = __expf(v.x);
    o.y = __expf(v.y);
    *(float2*)(out + (size_t)r * kN + pi) = o;
  }
}

// ---------- pre-pass B (fallback): bf16 packed into lower 128 B of rows ----
__global__ void exp_swizzle_bf16(const float* in, char* outbase) {
  const int total = kB * kT * 32;  // pairs
  int p = blockIdx.x * blockDim.x + threadIdx.x;
  const int stride = gridDim.x * blockDim.x;
  for (; p < total; p += stride) {
    const int r = p >> 5;
    const int j0 = (p & 31) << 1;
    const float2 v = *(const float2*)(in + (size_t)r * kN + j0);
    const float e0 = __expf(v.x), e1 = __expf(v.y);
    unsigned u0 = __float_as_uint(e0);
    u0 += 0x7FFFu + ((u0 >> 16) & 1u);  // RNE to bf16
    unsigned u1 = __float_as_uint(e1);
    u1 += 0x7FFFu + ((u1 >> 16) & 1u);
    const unsigned d = (u1 & 0xFFFF0000u) | (u0 >> 16);
    const int pi = ((j0 >> 2) & 3) * 16 + ((j0 >> 4) << 2) + (j0 & 3);
    *(unsigned*)(outbase + (size_t)r * 256 + pi * 2) = d;
  }
}

// ---------- helpers ----------
__device__ __forceinline__ unsigned pack2bf(float lo, float hi) {
  return __builtin_amdgcn_perm(__float_as_uint(hi), __float_as_uint(lo), 0x07060302u);
}

__device__ __forceinline__ f32x4 expand2(unsigned u, unsigned v) {
  f32x4 e;
  e.x = __uint_as_float(u << 16);
  e.y = __uint_as_float(u & 0xFFFF0000u);
  e.z = __uint_as_float(v << 16);
  e.w = __uint_as_float(v & 0xFFFF0000u);
  return e;
}

// One step: Q = E*Acc (8 MFMA), Acc' = Q .* e. e read from LDS row `lrow`.
template <bool F32>
__device__ __forceinline__ void step_lds(f32x4 (&ps)[4], const bf16x8 (&af)[4][2],
                                         const char* lrow) {
  f32x4 e0, e1, e2, e3;
  if constexpr (F32) {
    e0 = *(const f32x4*)(lrow + 0);
    e1 = *(const f32x4*)(lrow + 16);
    e2 = *(const f32x4*)(lrow + 32);
    e3 = *(const f32x4*)(lrow + 48);
  } else {
    const uint4 u0 = *(const uint4*)(lrow + 0);
    const uint4 u1 = *(const uint4*)(lrow + 16);
    e0 = expand2(u0.x, u0.y);
    e1 = expand2(u0.z, u0.w);
    e2 = expand2(u1.x, u1.y);
    e3 = expand2(u1.z, u1.w);
  }

  union { unsigned u[4]; bf16x8 s; } b0u, b1u;
  b0u.u[0] = pack2bf(ps[0].x, ps[0].y);
  b0u.u[1] = pack2bf(ps[0].z, ps[0].w);
  b0u.u[2] = pack2bf(ps[1].x, ps[1].y);
  b0u.u[3] = pack2bf(ps[1].z, ps[1].w);
  const bf16x8 b0 = b0u.s;
  const f32x4 z4 = {0.f, 0.f, 0.f, 0.f};
  f32x4 q0 = __builtin_amdgcn_mfma_f32_16x16x32_bf16(af[0][0], b0, z4, 0, 0, 0);
  f32x4 q1 = __builtin_amdgcn_mfma_f32_16x16x32_bf16(af[1][0], b0, z4, 0, 0, 0);
  f32x4 q2 = __builtin_amdgcn_mfma_f32_16x16x32_bf16(af[2][0], b0, z4, 0, 0, 0);
  f32x4 q3 = __builtin_amdgcn_mfma_f32_16x16x32_bf16(af[3][0], b0, z4, 0, 0, 0);
  b1u.u[0] = pack2bf(ps[2].x, ps[2].y);
  b1u.u[1] = pack2bf(ps[2].z, ps[2].w);
  b1u.u[2] = pack2bf(ps[3].x, ps[3].y);
  b1u.u[3] = pack2bf(ps[3].z, ps[3].w);
  const bf16x8 b1 = b1u.s;
  q0 = __builtin_amdgcn_mfma_f32_16x16x32_bf16(af[0][1], b1, q0, 0, 0, 0);
  q1 = __builtin_amdgcn_mfma_f32_16x16x32_bf16(af[1][1], b1, q1, 0, 0, 0);
  q2 = __builtin_amdgcn_mfma_f32_16x16x32_bf16(af[2][1], b1, q2, 0, 0, 0);
  q3 = __builtin_amdgcn_mfma_f32_16x16x32_bf16(af[3][1], b1, q3, 0, 0, 0);

  ps[0] = q0 * e0;
  ps[1] = q1 * e1;
  ps[2] = q2 * e2;
  ps[3] = q3 * e3;
}

// Per-wave renorm by exact power of 2 from lane 0's ps[0].x exponent.
// Spread bounded (~2^21); 4-step growth <= 2^56 -> max < 2^78, safe.
// Exact powers of 2: ps * 2^tot_e is invariant.
__device__ __forceinline__ void renorm(f32x4 (&ps)[4], float& tot_e) {
  const unsigned eref = __builtin_amdgcn_readfirstlane(__float_as_uint(ps[0].x));
  const int e = (int)((eref >> 23) & 0xFFu) - 127;
  const float sc = __uint_as_float((unsigned)(127 - e) << 23);
#pragma unroll
  for (int mt = 0; mt < 4; ++mt) ps[mt] *= sc;
  tot_e += (float)e;
}

__device__ __forceinline__ float exp2i(int d) {  // 2^d for d in [-126, 127]
  return (d <= -127) ? 0.f : __uint_as_float((unsigned)(127 + d) << 23);
}

// ---------- chunk-pair kernel: 256 threads = 4 waves x 2 chains ----------
template <bool F32>
__global__ __launch_bounds__(256, 3) void chunk_pair_kernel(
    const char* __restrict__ eu, const float* __restrict__ trans,
    const int* __restrict__ lengths, char* __restrict__ scr, int scrStride) {
  constexpr int RB = F32 ? 256 : 128;  // LDS row bytes
  constexpr int SEG = RB / 8;          // per-thread segment bytes
  constexpr int STG = 32 * RB;         // LDS stage bytes per chunk

  const int b = blockIdx.x >> 2;   // kC/2 = 4 pairs per batch
  const int cp = blockIdx.x & 3;
  const int len = lengths[b];
  const int cA = 2 * cp, cB = 2 * cp + 1;
  int stepsA = len - cA * kL;
  stepsA = stepsA < 0 ? 0 : (stepsA > kL ? kL : stepsA);
  int stepsB = len - cB * kL;
  stepsB = stepsB < 0 ? 0 : (stepsB > kL ? kL : stepsB);
  if (stepsA <= 0) return;  // then B inactive too (block-uniform)

  const int t8 = threadIdx.x;
  const int lane = t8 & 63;
  const int w = t8 >> 6;
  const int col = lane & 15;
  const int q4 = lane >> 4;

  // Static A-fragments, psi-permuted K (verified rounds 2-9).
  bf16x8 af[4][2];
#pragma unroll
  for (int mt = 0; mt < 4; ++mt) {
#pragma unroll
    for (int kc = 0; kc < 2; ++kc) {
      union { unsigned u[4]; bf16x8 s; } fr;
#pragma unroll
      for (int jp = 0; jp < 4; ++jp) {
        const int j0 = 2 * jp, j1 = 2 * jp + 1;
        const int k0 = (2 * kc + (j0 >> 2)) * 16 + q4 * 4 + (j0 & 3);
        const int k1 = (2 * kc + (j1 >> 2)) * 16 + q4 * 4 + (j1 & 3);
        unsigned e0 = __float_as_uint(__expf(trans[(mt * 16 + col) * kN + k0])) + 0x8000u;
        unsigned e1 = __float_as_uint(__expf(trans[(mt * 16 + col) * kN + k1])) + 0x8000u;
        fr.u[jp] = __builtin_amdgcn_perm(e1, e0, 0x07060302u);
      }
      af[mt][kc] = fr.s;
    }
  }

  // Acc = identity columns; this wave owns columns w*16..w*16+15 of BOTH
  // chunks of the pair.
  const int mycol = w * 16 + col;
  f32x4 psA[4], psB[4];
#pragma unroll
  for (int mt = 0; mt < 4; ++mt) {
    const int rb = mt * 16 + q4 * 4;
    f32x4 v;
    v.x = (rb + 0 == mycol) ? 1.f : 0.f;
    v.y = (rb + 1 == mycol) ? 1.f : 0.f;
    v.z = (rb + 2 == mycol) ? 1.f : 0.f;
    v.w = (rb + 3 == mycol) ? 1.f : 0.f;
    psA[mt] = v;
    psB[mt] = v;
  }

  // Staging geometry. eu rows are 256 B (f32 full row / bf16 in lower 128 B).
  // Both chunks' rows are always in-bounds of eu (chunk start + 255 < kT).
  const char* gblkA = eu + (size_t)(b * kT + cA * kL) * 256;
  const char* gblkB = eu + (size_t)(b * kT + cB * kL) * 256;
  const size_t gOff = (size_t)(t8 >> 3) * 256 + (size_t)(t8 & 7) * SEG;
  const size_t lOff = (size_t)(t8 >> 3) * RB + (size_t)(t8 & 7) * SEG;

  __shared__ __align__(16) char smem[2][2][STG];  // [chunk][buf][stage]

  // Preload stage 0 for both chunks.
  {
    uint4 vaA = *(const uint4*)(gblkA + gOff);
    uint4 vaB = *(const uint4*)(gblkB + gOff);
    uint4 vbA, vbB;
    if constexpr (F32) {
      vbA = *(const uint4*)(gblkA + gOff + 16);
      vbB = *(const uint4*)(gblkB + gOff + 16);
    }
    *(uint4*)(&smem[0][0][0] + lOff) = vaA;
    *(uint4*)(&smem[1][0][0] + lOff) = vaB;
    if constexpr (F32) {
      *(uint4*)(&smem[0][0][0] + lOff + 16) = vbA;
      *(uint4*)(&smem[1][0][0] + lOff + 16) = vbB;
    }
  }
  __syncthreads();

  float totA = 0.0f, totB = 0.0f;
  for (int s = 0; s < 8; ++s) {  // fixed cadence: 8 stages x 32 steps
    uint4 vaA, vbA, vaB, vbB;
    const bool more = (s < 7);
    if (more) {
      const char* gA = gblkA + (size_t)(s + 1) * 8192 + gOff;
      const char* gB = gblkB + (size_t)(s + 1) * 8192 + gOff;
      vaA = *(const uint4*)gA;
      vaB = *(const uint4*)gB;
      if constexpr (F32) {
        vbA = *(const uint4*)(gA + 16);
        vbB = *(const uint4*)(gB + 16);
      }
    }

    int nsA = stepsA - s * 32;
    nsA = nsA < 0 ? 0 : (nsA > 32 ? 32 : nsA);
    int nsB = stepsB - s * 32;
    nsB = nsB < 0 ? 0 : (nsB > 32 ? 32 : nsB);
    const char* lbA = &smem[0][s & 1][0] + q4 * (RB / 4);
    const char* lbB = &smem[1][s & 1][0] + q4 * (RB / 4);

    if (nsA == 32 && nsB == 32) {
      // Hot path: interleaved step-pairs (two independent MFMA chains).
      for (int g = 0; g < 8; ++g) {
#pragma unroll
        for (int k = 0; k < 4; ++k) {
          step_lds<F32>(psA, af, lbA + (g * 4 + k) * RB);
          step_lds<F32>(psB, af, lbB + (g * 4 + k) * RB);
        }
        renorm(psA, totA);
        renorm(psB, totB);
      }
    } else {
      // Tail stages: per-chain sequential (renorm only on executed steps).
      for (int i = 0; i < nsA; ++i) {
        step_lds<F32>(psA, af, lbA + (size_t)i * RB);
        if ((i & 3) == 3) renorm(psA, totA);
      }
      for (int i = 0; i < nsB; ++i) {
        step_lds<F32>(psB, af, lbB + (size_t)i * RB);
        if ((i & 3) == 3) renorm(psB, totB);
      }
    }

    if (more) {
      char* lA = &smem[0][(s + 1) & 1][0] + lOff;
      char* lB = &smem[1][(s + 1) & 1][0] + lOff;
      *(uint4*)lA = vaA;
      *(uint4*)lB = vaB;
      if constexpr (F32) {
        *(uint4*)(lA + 16) = vbA;
        *(uint4*)(lB + 16) = vbB;
      }
    }
    __syncthreads();
  }

  // Store 64x16 tiles, column-major flat index F = tile*1024 + col*64 + row,
  // mapped to scratch slots of 32 floats with byte stride scrStride.
  {
    const long tileIdx = ((long)b * kC + cA) * 4 + w;
#pragma unroll
    for (int mt = 0; mt < 4; ++mt) {
      const long slot = tileIdx * 32 + col * 2 + (mt >> 1);
      char* addr = scr + slot * (long)scrStride + ((mt & 1) * 16 + q4 * 4) * 4;
      *(f32x4*)addr = psA[mt];
    }
    if (lane == 0) {
      const long F = kTileFloats + tileIdx;
      *(float*)(scr + (F >> 5) * (long)scrStride + (F & 31) * 4) = totA;
    }
  }
  if (stepsB > 0) {
    const long tileIdx = ((long)b * kC + cB) * 4 + w;
#pragma unroll
    for (int mt = 0; mt < 4; ++mt) {
      const long slot = tileIdx * 32 + col * 2 + (mt >> 1);
      char* addr = scr + slot * (long)scrStride + ((mt & 1) * 16 + q4 * 4) * 4;
      *(f32x4*)addr = psB[mt];
    }
    if (lane == 0) {
      const long F = kTileFloats + tileIdx;
      *(float*)(scr + (F >> 5) * (long)scrStride + (F & 31) * 4) = totB;
    }
  }
}

// ---------- combine: per batch, chain the chunk matrices (one wave) ----------
__global__ __launch_bounds__(64) void combine_kernel(
    const char* __restrict__ scr, int scrStride, const float* __restrict__ trans,
    const int* __restrict__ lengths, float* __restrict__ out) {
  const int b = blockIdx.x;
  const int j = threadIdx.x;
  const int len = lengths[b];

#define LDS_SCR(F) (*(const float*)(scr + ((long)(F) >> 5) * (long)scrStride + ((F) & 31) * 4))

  // alpha after chunk 0 = column kStart of chunk-0 matrix (wave 0's tile).
  const long t0 = (long)b * kC * 4;
  float a = LDS_SCR(t0 * 1024 + kStart * 64 + j);
  float totE = LDS_SCR(kTileFloats + t0);

  for (int c = 1; c < kC; ++c) {
    if (c * kL >= len) break;  // chunks are contiguous-active
    const long tb = ((long)b * kC + c) * 4;
    float s0 = 0.f, s1 = 0.f, s2 = 0.f, s3 = 0.f;
#pragma unroll
    for (int k16 = 0; k16 < 16; ++k16) {
      const float a0 = __int_as_float(__builtin_amdgcn_readlane(__float_as_int(a), k16));
      const float a1 = __int_as_float(__builtin_amdgcn_readlane(__float_as_int(a), 16 + k16));
      const float a2 = __int_as_float(__builtin_amdgcn_readlane(__float_as_int(a), 32 + k16));
      const float a3 = __int_as_float(__builtin_amdgcn_readlane(__float_as_int(a), 48 + k16));
      s0 = fmaf(LDS_SCR((tb + 0) * 1024 + k16 * 64 + j), a0, s0);
      s1 = fmaf(LDS_SCR((tb + 1) * 1024 + k16 * 64 + j), a1, s1);
      s2 = fmaf(LDS_SCR((tb + 2) * 1024 + k16 * 64 + j), a2, s2);
      s3 = fmaf(LDS_SCR((tb + 3) * 1024 + k16 * 64 + j), a3, s3);
    }
    const float e0 = LDS_SCR(kTileFloats + tb + 0);
    const float e1 = LDS_SCR(kTileFloats + tb + 1);
    const float e2 = LDS_SCR(kTileFloats + tb + 2);
    const float e3 = LDS_SCR(kTileFloats + tb + 3);
    const float em = fmaxf(fmaxf(e0, e1), fmaxf(e2, e3));
    a = s0 * exp2i((int)(e0 - em)) + s1 * exp2i((int)(e1 - em)) +
        s2 * exp2i((int)(e2 - em)) + s3 * exp2i((int)(e3 - em));
    totE += em;

    // renorm alpha (exact power of 2 from the wave max)
    float m = a;
#pragma unroll
    for (int mask = 1; mask < 64; mask <<= 1) m = fmaxf(m, __shfl_xor(m, mask));
    const int e = (int)((__float_as_uint(m) >> 23) & 0xFFu) - 127;
    a *= exp2i(-e);
    totE += (float)e;
  }

  float term = a * __expf(trans[kEnd * kN + j]);
#pragma unroll
  for (int mask = 1; mask < 64; mask <<= 1) term += __shfl_xor(term, mask);

  if (j == 0) out[b] = totE * 0.69314718055994530942f + logf(term);
#undef LDS_SCR
}

extern "C" void kernel_launch(void* const* d_in, const int* in_sizes, int n_in,
                              void* d_out, int out_size, void* d_ws, size_t ws_size,
                              hipStream_t stream) {
  const float* unary = (const float*)d_in[0];  // [B, T, N] fp32, 128 MiB
  const float* trans = (const float*)d_in[1];  // [N, N] fp32
  const int* lengths = (const int*)d_in[2];    // [B] int32
  float* out = (float*)d_out;                  // [B] fp32

  const size_t euBytes = (size_t)kB * kT * 256;                   // 128 MiB
  const size_t scrBytes = (size_t)(kTileFloats + kNumTiles) * 4;  // ~33.6 MB

  if (ws_size >= euBytes + scrBytes) {
    // No-clobber: exp table in workspace; d_in[0] untouched.
    exp_swizzle_f32_out<<<dim3(4096), dim3(256), 0, stream>>>(unary, (float*)d_ws);
    chunk_pair_kernel<true><<<dim3(kB * 4), dim3(256), 0, stream>>>(
        (const char*)d_ws, trans, lengths, (char*)d_ws + euBytes, 128);
    combine_kernel<<<dim3(kB), dim3(64), 0, stream>>>(
        (const char*)d_ws + euBytes, 128, trans, lengths, out);
  } else if (ws_size >= scrBytes) {
    // In-place exp table over d_in[0]; tiles in workspace.
    exp_swizzle_f32<<<dim3(4096), dim3(256), 0, stream>>>((float*)d_in[0]);
    chunk_pair_kernel<true><<<dim3(kB * 4), dim3(256), 0, stream>>>(
        (const char*)d_in[0], trans, lengths, (char*)d_ws, 128);
    combine_kernel<<<dim3(kB), dim3(64), 0, stream>>>((char*)d_ws, 128,
                                                      trans, lengths, out);
  } else {
    // Fallback: bf16 eu in lower 128 B of each 256-B row of d_in[0]; tiles
    // in the upper 128 B halves (byte-disjoint; harness restores inputs).
    exp_swizzle_bf16<<<dim3(4096), dim3(256), 0, stream>>>(unary, (char*)d_in[0]);
    chunk_pair_kernel<false><<<dim3(kB * 4), dim3(256), 0, stream>>>(
        (const char*)d_in[0], trans, lengths, (char*)d_in[0] + 128, 256);
    combine_kernel<<<dim3(kB), dim3(64), 0, stream>>>((const char*)d_in[0] + 128,
                                                      256, trans, lengths, out);
  }
}

// Round 4
// 410.321 us; speedup vs baseline: 1.8363x; 1.2075x over previous
//
#include <hip/hip_runtime.h>

// CRF forward (log partition), B=256, T=2048, N=64, MI355X.
//
// Round 11: one wave = one whole chunk matrix (64x64), exp fused into
// staging, no pre-pass, no barriers.
// Post-mortem r7-r10: ~600 cy wall per step per wave is invariant to
// LDS-vs-global, chain count, and dual-chain-per-wave; per-wave matrix work
// was only ~155 cy/step (8 MFMA) -> MfmaUtil pinned at ~32%. Fix: ps[4][4]
// (all 64 columns) -> 32 MFMA = ~620 cy pipe work per step per wave, which
// exceeds the serial wall, so 2 waves/SIMD oversubscribe the matrix pipe
// and the kernel is MFMA-throughput-bound independent of latency details.
//  - grid = B*kC = 2048 single-wave blocks (= 2 waves/SIMD exactly);
//    __launch_bounds__(64,2) -> 256-reg budget, no spill for ~160 live.
//  - Per-wave LDS staging (2x4KB dbuf, 16 rows/stage), no __syncthreads:
//    wave self-syncs via compiler waitcnts. exp + psi-permute fused into
//    the staging (psi moves 16B groups as units), raw unary read directly.
//  - combine unchanged (proven). Old bf16 in-place path kept as fallback
//    for ws < 34 MB only.

typedef __attribute__((ext_vector_type(4))) float f32x4;
typedef __attribute__((ext_vector_type(8))) short bf16x8;

namespace {
constexpr int kB = 256;
constexpr int kT = 2048;
constexpr int kN = 64;
constexpr int kC = 8;        // chunks per sequence
constexpr int kL = kT / kC;  // 256 steps per chunk
constexpr int kStart = 1;    // GO
constexpr int kEnd = 2;      // EOS
constexpr long kTileFloats = (long)kB * kC * 4 * 1024;  // 8192 tiles x 64x16
constexpr long kNumTiles = (long)kB * kC * 4;
}  // namespace

// ---------- helpers ----------
__device__ __forceinline__ unsigned pack2bf(float lo, float hi) {
  return __builtin_amdgcn_perm(__float_as_uint(hi), __float_as_uint(lo), 0x07060302u);
}

__device__ __forceinline__ f32x4 expand2(unsigned u, unsigned v) {
  f32x4 e;
  e.x = __uint_as_float(u << 16);
  e.y = __uint_as_float(u & 0xFFFF0000u);
  e.z = __uint_as_float(v << 16);
  e.w = __uint_as_float(v & 0xFFFF0000u);
  return e;
}

__device__ __forceinline__ f32x4 exp4(f32x4 v) {
  f32x4 r;
  r.x = __expf(v.x);
  r.y = __expf(v.y);
  r.z = __expf(v.z);
  r.w = __expf(v.w);
  return r;
}

__device__ __forceinline__ float exp2i(int d) {  // 2^d for d in [-126, 127]
  return (d <= -127) ? 0.f : __uint_as_float((unsigned)(127 + d) << 23);
}

// ---------- full-matrix step: Q = E*Acc (32 MFMA), Acc' = Q .* e ----------
// ps[nt][mt]: C tile rows mt*16+q4*4.., cols nt*16+col. e row broadcast
// (depends on row only), loaded once, reused across the 4 independent
// N-tiles -> 4 parallel pack->MFMA->mul chains per step.
__device__ __forceinline__ void step64(f32x4 (&ps)[4][4], const bf16x8 (&af)[4][2],
                                       const char* lrow) {
  const f32x4 e0 = *(const f32x4*)(lrow + 0);
  const f32x4 e1 = *(const f32x4*)(lrow + 16);
  const f32x4 e2 = *(const f32x4*)(lrow + 32);
  const f32x4 e3 = *(const f32x4*)(lrow + 48);
  const f32x4 z4 = {0.f, 0.f, 0.f, 0.f};
#pragma unroll
  for (int nt = 0; nt < 4; ++nt) {
    union { unsigned u[4]; bf16x8 s; } b0u, b1u;
    b0u.u[0] = pack2bf(ps[nt][0].x, ps[nt][0].y);
    b0u.u[1] = pack2bf(ps[nt][0].z, ps[nt][0].w);
    b0u.u[2] = pack2bf(ps[nt][1].x, ps[nt][1].y);
    b0u.u[3] = pack2bf(ps[nt][1].z, ps[nt][1].w);
    b1u.u[0] = pack2bf(ps[nt][2].x, ps[nt][2].y);
    b1u.u[1] = pack2bf(ps[nt][2].z, ps[nt][2].w);
    b1u.u[2] = pack2bf(ps[nt][3].x, ps[nt][3].y);
    b1u.u[3] = pack2bf(ps[nt][3].z, ps[nt][3].w);
    const bf16x8 b0 = b0u.s, b1 = b1u.s;
    f32x4 q0 = __builtin_amdgcn_mfma_f32_16x16x32_bf16(af[0][0], b0, z4, 0, 0, 0);
    f32x4 q1 = __builtin_amdgcn_mfma_f32_16x16x32_bf16(af[1][0], b0, z4, 0, 0, 0);
    f32x4 q2 = __builtin_amdgcn_mfma_f32_16x16x32_bf16(af[2][0], b0, z4, 0, 0, 0);
    f32x4 q3 = __builtin_amdgcn_mfma_f32_16x16x32_bf16(af[3][0], b0, z4, 0, 0, 0);
    q0 = __builtin_amdgcn_mfma_f32_16x16x32_bf16(af[0][1], b1, q0, 0, 0, 0);
    q1 = __builtin_amdgcn_mfma_f32_16x16x32_bf16(af[1][1], b1, q1, 0, 0, 0);
    q2 = __builtin_amdgcn_mfma_f32_16x16x32_bf16(af[2][1], b1, q2, 0, 0, 0);
    q3 = __builtin_amdgcn_mfma_f32_16x16x32_bf16(af[3][1], b1, q3, 0, 0, 0);
    ps[nt][0] = q0 * e0;
    ps[nt][1] = q1 * e1;
    ps[nt][2] = q2 * e2;
    ps[nt][3] = q3 * e3;
  }
}

// Renorm all 16 tiles by exact power of 2 from lane 0's ps[0][0].x exponent.
// Entry spread across the 64x64 matrix bounded (~2^21); 4-step growth
// <= 2^56 -> max < 2^78, safe in f32.
__device__ __forceinline__ void renorm64(f32x4 (&ps)[4][4], float& tot_e) {
  const unsigned eref = __builtin_amdgcn_readfirstlane(__float_as_uint(ps[0][0].x));
  const int e = (int)((eref >> 23) & 0xFFu) - 127;
  const float sc = __uint_as_float((unsigned)(127 - e) << 23);
#pragma unroll
  for (int nt = 0; nt < 4; ++nt)
#pragma unroll
    for (int mt = 0; mt < 4; ++mt) ps[nt][mt] *= sc;
  tot_e += (float)e;
}

// ---------- chunk kernel: 1 wave = 1 chunk, all 64 columns ----------
__global__ __launch_bounds__(64, 2) void chunk64_kernel(
    const char* __restrict__ un, const float* __restrict__ trans,
    const int* __restrict__ lengths, char* __restrict__ scr, int scrStride) {
  const int b = blockIdx.x >> 3;
  const int c = blockIdx.x & 7;
  const int len = lengths[b];
  const int start = c * kL;
  int steps = len - start;
  if (steps <= 0) return;
  if (steps > kL) steps = kL;

  const int lane = threadIdx.x & 63;
  const int col = lane & 15;
  const int q4 = lane >> 4;

  // Static A-fragments, psi-permuted K (verified rounds 2-10).
  bf16x8 af[4][2];
#pragma unroll
  for (int mt = 0; mt < 4; ++mt) {
#pragma unroll
    for (int kc = 0; kc < 2; ++kc) {
      union { unsigned u[4]; bf16x8 s; } fr;
#pragma unroll
      for (int jp = 0; jp < 4; ++jp) {
        const int j0 = 2 * jp, j1 = 2 * jp + 1;
        const int k0 = (2 * kc + (j0 >> 2)) * 16 + q4 * 4 + (j0 & 3);
        const int k1 = (2 * kc + (j1 >> 2)) * 16 + q4 * 4 + (j1 & 3);
        unsigned e0 = __float_as_uint(__expf(trans[(mt * 16 + col) * kN + k0])) + 0x8000u;
        unsigned e1 = __float_as_uint(__expf(trans[(mt * 16 + col) * kN + k1])) + 0x8000u;
        fr.u[jp] = __builtin_amdgcn_perm(e1, e0, 0x07060302u);
      }
      af[mt][kc] = fr.s;
    }
  }

  // Acc = identity: ps[nt][mt], element (row, col) with row = mt*16+q4*4+i,
  // col = nt*16 + (lane&15).
  f32x4 ps[4][4];
#pragma unroll
  for (int nt = 0; nt < 4; ++nt) {
    const int mycol = nt * 16 + col;
#pragma unroll
    for (int mt = 0; mt < 4; ++mt) {
      const int rb = mt * 16 + q4 * 4;
      f32x4 v;
      v.x = (rb + 0 == mycol) ? 1.f : 0.f;
      v.y = (rb + 1 == mycol) ? 1.f : 0.f;
      v.z = (rb + 2 == mycol) ? 1.f : 0.f;
      v.w = (rb + 3 == mycol) ? 1.f : 0.f;
      ps[nt][mt] = v;
    }
  }

  // Per-wave staging: 16 raw unary rows (256 B each) per stage, exp +
  // psi-permute applied en route (psi = digit swap j=16a+4b+c -> 16b+4a+c,
  // so 16B segments move as units: global (row, i*64 + sb*16) -> LDS
  // (row, sb*64 + i*16)). No barriers: wave self-syncs via waitcnts.
  const char* gbase = un + (size_t)(b * kT + start) * 256;
  const int srow = lane >> 2;  // 0..15
  const int sb = lane & 3;     // 0..3
  const size_t gRow = (size_t)srow * 256;

  __shared__ __align__(16) char sm[2][4096];

  {  // preload stage 0
    const char* g = gbase + gRow + sb * 16;
    f32x4 v0 = exp4(*(const f32x4*)(g + 0));
    f32x4 v1 = exp4(*(const f32x4*)(g + 64));
    f32x4 v2 = exp4(*(const f32x4*)(g + 128));
    f32x4 v3 = exp4(*(const f32x4*)(g + 192));
    char* l = &sm[0][0] + gRow + (size_t)sb * 64;
    *(f32x4*)(l + 0) = v0;
    *(f32x4*)(l + 16) = v1;
    *(f32x4*)(l + 32) = v2;
    *(f32x4*)(l + 48) = v3;
  }

  float tot_e = 0.0f;
  const int nst = (steps + 15) >> 4;
  for (int s = 0; s < nst; ++s) {
    f32x4 v0, v1, v2, v3;
    const bool more = (s + 1 < nst);
    if (more) {  // issue next stage's raw loads now; consume after compute
      const char* g = gbase + (size_t)(s + 1) * 4096 + gRow + sb * 16;
      v0 = *(const f32x4*)(g + 0);
      v1 = *(const f32x4*)(g + 64);
      v2 = *(const f32x4*)(g + 128);
      v3 = *(const f32x4*)(g + 192);
    }

    int ns = steps - s * 16;
    ns = ns > 16 ? 16 : ns;
    const char* lb = &sm[s & 1][0] + q4 * 64;
    if (ns == 16) {
      const char* l2 = lb;
#pragma unroll 1
      for (int g4 = 0; g4 < 4; ++g4) {
        step64(ps, af, l2 + 0);
        step64(ps, af, l2 + 256);
        step64(ps, af, l2 + 512);
        step64(ps, af, l2 + 768);
        renorm64(ps, tot_e);
        l2 += 1024;
      }
    } else {
      for (int i = 0; i < ns; ++i) {
        step64(ps, af, lb + (size_t)i * 256);
        if ((i & 3) == 3) renorm64(ps, tot_e);
      }
    }

    if (more) {
      char* l = &sm[(s + 1) & 1][0] + gRow + (size_t)sb * 64;
      *(f32x4*)(l + 0) = exp4(v0);
      *(f32x4*)(l + 16) = exp4(v1);
      *(f32x4*)(l + 32) = exp4(v2);
      *(f32x4*)(l + 48) = exp4(v3);
    }
  }

  // Store 4 x (64x16) tiles, same scratch format as prior rounds:
  // flat F = tile*1024 + col*64 + row -> slot of 32 floats, byte stride
  // scrStride. tot_e duplicated per tile (combine reads per-tile e).
  const long tbase = ((long)b * kC + c) * 4;
#pragma unroll
  for (int nt = 0; nt < 4; ++nt) {
    const long tileIdx = tbase + nt;
#pragma unroll
    for (int mt = 0; mt < 4; ++mt) {
      const long slot = tileIdx * 32 + col * 2 + (mt >> 1);
      char* addr = scr + slot * (long)scrStride + ((mt & 1) * 16 + q4 * 4) * 4;
      *(f32x4*)addr = ps[nt][mt];
    }
    if (lane == 0) {
      const long F = kTileFloats + tileIdx;
      *(float*)(scr + (F >> 5) * (long)scrStride + (F & 31) * 4) = tot_e;
    }
  }
}

// ---------- combine: per batch, chain the chunk matrices (one wave) ----------
__global__ __launch_bounds__(64) void combine_kernel(
    const char* __restrict__ scr, int scrStride, const float* __restrict__ trans,
    const int* __restrict__ lengths, float* __restrict__ out) {
  const int b = blockIdx.x;
  const int j = threadIdx.x;
  const int len = lengths[b];

#define LDS_SCR(F) (*(const float*)(scr + ((long)(F) >> 5) * (long)scrStride + ((F) & 31) * 4))

  // alpha after chunk 0 = column kStart of chunk-0 matrix.
  const long t0 = (long)b * kC * 4;
  float a = LDS_SCR(t0 * 1024 + kStart * 64 + j);
  float totE = LDS_SCR(kTileFloats + t0);

  for (int c = 1; c < kC; ++c) {
    if (c * kL >= len) break;  // chunks are contiguous-active
    const long tb = ((long)b * kC + c) * 4;
    float s0 = 0.f, s1 = 0.f, s2 = 0.f, s3 = 0.f;
#pragma unroll
    for (int k16 = 0; k16 < 16; ++k16) {
      const float a0 = __int_as_float(__builtin_amdgcn_readlane(__float_as_int(a), k16));
      const float a1 = __int_as_float(__builtin_amdgcn_readlane(__float_as_int(a), 16 + k16));
      const float a2 = __int_as_float(__builtin_amdgcn_readlane(__float_as_int(a), 32 + k16));
      const float a3 = __int_as_float(__builtin_amdgcn_readlane(__float_as_int(a), 48 + k16));
      s0 = fmaf(LDS_SCR((tb + 0) * 1024 + k16 * 64 + j), a0, s0);
      s1 = fmaf(LDS_SCR((tb + 1) * 1024 + k16 * 64 + j), a1, s1);
      s2 = fmaf(LDS_SCR((tb + 2) * 1024 + k16 * 64 + j), a2, s2);
      s3 = fmaf(LDS_SCR((tb + 3) * 1024 + k16 * 64 + j), a3, s3);
    }
    const float e0 = LDS_SCR(kTileFloats + tb + 0);
    const float e1 = LDS_SCR(kTileFloats + tb + 1);
    const float e2 = LDS_SCR(kTileFloats + tb + 2);
    const float e3 = LDS_SCR(kTileFloats + tb + 3);
    const float em = fmaxf(fmaxf(e0, e1), fmaxf(e2, e3));
    a = s0 * exp2i((int)(e0 - em)) + s1 * exp2i((int)(e1 - em)) +
        s2 * exp2i((int)(e2 - em)) + s3 * exp2i((int)(e3 - em));
    totE += em;

    // renorm alpha (exact power of 2 from the wave max)
    float m = a;
#pragma unroll
    for (int mask = 1; mask < 64; mask <<= 1) m = fmaxf(m, __shfl_xor(m, mask));
    const int e = (int)((__float_as_uint(m) >> 23) & 0xFFu) - 127;
    a *= exp2i(-e);
    totE += (float)e;
  }

  float term = a * __expf(trans[kEnd * kN + j]);
#pragma unroll
  for (int mask = 1; mask < 64; mask <<= 1) term += __shfl_xor(term, mask);

  if (j == 0) out[b] = totE * 0.69314718055994530942f + logf(term);
#undef LDS_SCR
}

// ================= fallback machinery (ws < scratch): r10 path =============
__global__ void exp_swizzle_bf16(const float* in, char* outbase) {
  const int total = kB * kT * 32;  // pairs
  int p = blockIdx.x * blockDim.x + threadIdx.x;
  const int stride = gridDim.x * blockDim.x;
  for (; p < total; p += stride) {
    const int r = p >> 5;
    const int j0 = (p & 31) << 1;
    const float2 v = *(const float2*)(in + (size_t)r * kN + j0);
    const float e0 = __expf(v.x), e1 = __expf(v.y);
    unsigned u0 = __float_as_uint(e0);
    u0 += 0x7FFFu + ((u0 >> 16) & 1u);  // RNE to bf16
    unsigned u1 = __float_as_uint(e1);
    u1 += 0x7FFFu + ((u1 >> 16) & 1u);
    const unsigned d = (u1 & 0xFFFF0000u) | (u0 >> 16);
    const int pi = ((j0 >> 2) & 3) * 16 + ((j0 >> 4) << 2) + (j0 & 3);
    *(unsigned*)(outbase + (size_t)r * 256 + pi * 2) = d;
  }
}

__device__ __forceinline__ void step_lds_bf16(f32x4 (&ps)[4], const bf16x8 (&af)[4][2],
                                              const char* lrow) {
  const uint4 u0 = *(const uint4*)(lrow + 0);
  const uint4 u1 = *(const uint4*)(lrow + 16);
  f32x4 e0 = expand2(u0.x, u0.y);
  f32x4 e1 = expand2(u0.z, u0.w);
  f32x4 e2 = expand2(u1.x, u1.y);
  f32x4 e3 = expand2(u1.z, u1.w);

  union { unsigned u[4]; bf16x8 s; } b0u, b1u;
  b0u.u[0] = pack2bf(ps[0].x, ps[0].y);
  b0u.u[1] = pack2bf(ps[0].z, ps[0].w);
  b0u.u[2] = pack2bf(ps[1].x, ps[1].y);
  b0u.u[3] = pack2bf(ps[1].z, ps[1].w);
  const bf16x8 b0 = b0u.s;
  const f32x4 z4 = {0.f, 0.f, 0.f, 0.f};
  f32x4 q0 = __builtin_amdgcn_mfma_f32_16x16x32_bf16(af[0][0], b0, z4, 0, 0, 0);
  f32x4 q1 = __builtin_amdgcn_mfma_f32_16x16x32_bf16(af[1][0], b0, z4, 0, 0, 0);
  f32x4 q2 = __builtin_amdgcn_mfma_f32_16x16x32_bf16(af[2][0], b0, z4, 0, 0, 0);
  f32x4 q3 = __builtin_amdgcn_mfma_f32_16x16x32_bf16(af[3][0], b0, z4, 0, 0, 0);
  b1u.u[0] = pack2bf(ps[2].x, ps[2].y);
  b1u.u[1] = pack2bf(ps[2].z, ps[2].w);
  b1u.u[2] = pack2bf(ps[3].x, ps[3].y);
  b1u.u[3] = pack2bf(ps[3].z, ps[3].w);
  const bf16x8 b1 = b1u.s;
  q0 = __builtin_amdgcn_mfma_f32_16x16x32_bf16(af[0][1], b1, q0, 0, 0, 0);
  q1 = __builtin_amdgcn_mfma_f32_16x16x32_bf16(af[1][1], b1, q1, 0, 0, 0);
  q2 = __builtin_amdgcn_mfma_f32_16x16x32_bf16(af[2][1], b1, q2, 0, 0, 0);
  q3 = __builtin_amdgcn_mfma_f32_16x16x32_bf16(af[3][1], b1, q3, 0, 0, 0);

  ps[0] = q0 * e0;
  ps[1] = q1 * e1;
  ps[2] = q2 * e2;
  ps[3] = q3 * e3;
}

__device__ __forceinline__ void renorm16(f32x4 (&ps)[4], float& tot_e) {
  const unsigned eref = __builtin_amdgcn_readfirstlane(__float_as_uint(ps[0].x));
  const int e = (int)((eref >> 23) & 0xFFu) - 127;
  const float sc = __uint_as_float((unsigned)(127 - e) << 23);
#pragma unroll
  for (int mt = 0; mt < 4; ++mt) ps[mt] *= sc;
  tot_e += (float)e;
}

__global__ __launch_bounds__(256, 3) void chunk_pair_bf16_kernel(
    const char* __restrict__ eu, const float* __restrict__ trans,
    const int* __restrict__ lengths, char* __restrict__ scr, int scrStride) {
  constexpr int RB = 128;
  constexpr int SEG = RB / 8;
  constexpr int STG = 32 * RB;

  const int b = blockIdx.x >> 2;
  const int cp = blockIdx.x & 3;
  const int len = lengths[b];
  const int cA = 2 * cp, cB = 2 * cp + 1;
  int stepsA = len - cA * kL;
  stepsA = stepsA < 0 ? 0 : (stepsA > kL ? kL : stepsA);
  int stepsB = len - cB * kL;
  stepsB = stepsB < 0 ? 0 : (stepsB > kL ? kL : stepsB);
  if (stepsA <= 0) return;

  const int t8 = threadIdx.x;
  const int lane = t8 & 63;
  const int w = t8 >> 6;
  const int col = lane & 15;
  const int q4 = lane >> 4;

  bf16x8 af[4][2];
#pragma unroll
  for (int mt = 0; mt < 4; ++mt) {
#pragma unroll
    for (int kc = 0; kc < 2; ++kc) {
      union { unsigned u[4]; bf16x8 s; } fr;
#pragma unroll
      for (int jp = 0; jp < 4; ++jp) {
        const int j0 = 2 * jp, j1 = 2 * jp + 1;
        const int k0 = (2 * kc + (j0 >> 2)) * 16 + q4 * 4 + (j0 & 3);
        const int k1 = (2 * kc + (j1 >> 2)) * 16 + q4 * 4 + (j1 & 3);
        unsigned e0 = __float_as_uint(__expf(trans[(mt * 16 + col) * kN + k0])) + 0x8000u;
        unsigned e1 = __float_as_uint(__expf(trans[(mt * 16 + col) * kN + k1])) + 0x8000u;
        fr.u[jp] = __builtin_amdgcn_perm(e1, e0, 0x07060302u);
      }
      af[mt][kc] = fr.s;
    }
  }

  const int mycol = w * 16 + col;
  f32x4 psA[4], psB[4];
#pragma unroll
  for (int mt = 0; mt < 4; ++mt) {
    const int rb = mt * 16 + q4 * 4;
    f32x4 v;
    v.x = (rb + 0 == mycol) ? 1.f : 0.f;
    v.y = (rb + 1 == mycol) ? 1.f : 0.f;
    v.z = (rb + 2 == mycol) ? 1.f : 0.f;
    v.w = (rb + 3 == mycol) ? 1.f : 0.f;
    psA[mt] = v;
    psB[mt] = v;
  }

  const char* gblkA = eu + (size_t)(b * kT + cA * kL) * 256;
  const char* gblkB = eu + (size_t)(b * kT + cB * kL) * 256;
  const size_t gOff = (size_t)(t8 >> 3) * 256 + (size_t)(t8 & 7) * SEG;
  const size_t lOff = (size_t)(t8 >> 3) * RB + (size_t)(t8 & 7) * SEG;

  __shared__ __align__(16) char smem[2][2][STG];

  {
    uint4 vaA = *(const uint4*)(gblkA + gOff);
    uint4 vaB = *(const uint4*)(gblkB + gOff);
    *(uint4*)(&smem[0][0][0] + lOff) = vaA;
    *(uint4*)(&smem[1][0][0] + lOff) = vaB;
  }
  __syncthreads();

  float totA = 0.0f, totB = 0.0f;
  for (int s = 0; s < 8; ++s) {
    uint4 vaA, vaB;
    const bool more = (s < 7);
    if (more) {
      vaA = *(const uint4*)(gblkA + (size_t)(s + 1) * 8192 + gOff);
      vaB = *(const uint4*)(gblkB + (size_t)(s + 1) * 8192 + gOff);
    }

    int nsA = stepsA - s * 32;
    nsA = nsA < 0 ? 0 : (nsA > 32 ? 32 : nsA);
    int nsB = stepsB - s * 32;
    nsB = nsB < 0 ? 0 : (nsB > 32 ? 32 : nsB);
    const char* lbA = &smem[0][s & 1][0] + q4 * (RB / 4);
    const char* lbB = &smem[1][s & 1][0] + q4 * (RB / 4);

    if (nsA == 32 && nsB == 32) {
      for (int g = 0; g < 8; ++g) {
#pragma unroll
        for (int k = 0; k < 4; ++k) {
          step_lds_bf16(psA, af, lbA + (g * 4 + k) * RB);
          step_lds_bf16(psB, af, lbB + (g * 4 + k) * RB);
        }
        renorm16(psA, totA);
        renorm16(psB, totB);
      }
    } else {
      for (int i = 0; i < nsA; ++i) {
        step_lds_bf16(psA, af, lbA + (size_t)i * RB);
        if ((i & 3) == 3) renorm16(psA, totA);
      }
      for (int i = 0; i < nsB; ++i) {
        step_lds_bf16(psB, af, lbB + (size_t)i * RB);
        if ((i & 3) == 3) renorm16(psB, totB);
      }
    }

    if (more) {
      *(uint4*)(&smem[0][(s + 1) & 1][0] + lOff) = vaA;
      *(uint4*)(&smem[1][(s + 1) & 1][0] + lOff) = vaB;
    }
    __syncthreads();
  }

  {
    const long tileIdx = ((long)b * kC + cA) * 4 + w;
#pragma unroll
    for (int mt = 0; mt < 4; ++mt) {
      const long slot = tileIdx * 32 + col * 2 + (mt >> 1);
      char* addr = scr + slot * (long)scrStride + ((mt & 1) * 16 + q4 * 4) * 4;
      *(f32x4*)addr = psA[mt];
    }
    if (lane == 0) {
      const long F = kTileFloats + tileIdx;
      *(float*)(scr + (F >> 5) * (long)scrStride + (F & 31) * 4) = totA;
    }
  }
  if (stepsB > 0) {
    const long tileIdx = ((long)b * kC + cB) * 4 + w;
#pragma unroll
    for (int mt = 0; mt < 4; ++mt) {
      const long slot = tileIdx * 32 + col * 2 + (mt >> 1);
      char* addr = scr + slot * (long)scrStride + ((mt & 1) * 16 + q4 * 4) * 4;
      *(f32x4*)addr = psB[mt];
    }
    if (lane == 0) {
      const long F = kTileFloats + tileIdx;
      *(float*)(scr + (F >> 5) * (long)scrStride + (F & 31) * 4) = totB;
    }
  }
}

extern "C" void kernel_launch(void* const* d_in, const int* in_sizes, int n_in,
                              void* d_out, int out_size, void* d_ws, size_t ws_size,
                              hipStream_t stream) {
  const float* unary = (const float*)d_in[0];  // [B, T, N] fp32, 128 MiB
  const float* trans = (const float*)d_in[1];  // [N, N] fp32
  const int* lengths = (const int*)d_in[2];    // [B] int32
  float* out = (float*)d_out;                  // [B] fp32

  const size_t scrBytes = (size_t)(kTileFloats + kNumTiles) * 4;  // ~33.6 MB

  if (ws_size >= scrBytes) {
    // Primary: read raw unary directly (exp fused into staging); tiles in
    // workspace; inputs never written.
    chunk64_kernel<<<dim3(kB * kC), dim3(64), 0, stream>>>(
        (const char*)d_in[0], trans, lengths, (char*)d_ws, 128);
    combine_kernel<<<dim3(kB), dim3(64), 0, stream>>>((const char*)d_ws, 128,
                                                      trans, lengths, out);
  } else {
    // Fallback: bf16 eu in lower 128 B of each 256-B row of d_in[0]; tiles
    // in the upper 128 B halves (byte-disjoint; harness restores inputs).
    exp_swizzle_bf16<<<dim3(4096), dim3(256), 0, stream>>>(unary, (char*)d_in[0]);
    chunk_pair_bf16_kernel<<<dim3(kB * 4), dim3(256), 0, stream>>>(
        (const char*)d_in[0], trans, lengths, (char*)d_in[0] + 128, 256);
    combine_kernel<<<dim3(kB), dim3(64), 0, stream>>>((const char*)d_in[0] + 128,
                                                      256, trans, lengths, out);
  }
}

// Round 5
// 391.837 us; speedup vs baseline: 1.9230x; 1.0472x over previous
//
#include <hip/hip_runtime.h>

// CRF forward (log partition), B=256, T=2048, N=64, MI355X.
//
// Round 12: 32-column waves (2 nt-tiles, 16 MFMA/step) + pipelined combine.
// Post-mortem r11: 64-col waves (ps[4][4]=64 f32, live ~176) forced AGPR
// marshalling and serialized the 4 nt-chains -> wall/step ~2344 cy vs
// 620 cy MFMA issue; MfmaUtil pinned at 32% in r7/r10/r11 with VALUBusy
// always ~= MfmaUtil (marshal VALU ~ matrix work). Fix: the 64 chunk
// columns are INDEPENDENT (Acc'=diag(e)E*Acc is column-wise), so split
// each chunk across 2 single-wave blocks of 32 columns: live set ~120 regs
// -> no marshal, 2 interleavable chains, 3 waves/SIMD (launch_bounds(64,3),
// 170-reg cap). Grid 4096. Per-SIMD MFMA demand 3x310 cy/step vs ~1000 cy
// wall -> pipe mostly fed.
//  - Staging machinery (per-wave LDS dbuf, exp+psi fused, no barriers)
//    copied verbatim from r11.
//  - combine: prefetch chunk c+1's matrix (64 f32/lane) + e's into regs
//    during chunk c's serial chain; fully unrolled ping-pong.
//  - bf16 in-place fallback for ws < 34 MB kept from r11.

typedef __attribute__((ext_vector_type(4))) float f32x4;
typedef __attribute__((ext_vector_type(8))) short bf16x8;

namespace {
constexpr int kB = 256;
constexpr int kT = 2048;
constexpr int kN = 64;
constexpr int kC = 8;        // chunks per sequence
constexpr int kL = kT / kC;  // 256 steps per chunk
constexpr int kStart = 1;    // GO
constexpr int kEnd = 2;      // EOS
constexpr long kTileFloats = (long)kB * kC * 4 * 1024;  // 8192 tiles x 64x16
constexpr long kNumTiles = (long)kB * kC * 4;
}  // namespace

// ---------- helpers ----------
__device__ __forceinline__ unsigned pack2bf(float lo, float hi) {
  return __builtin_amdgcn_perm(__float_as_uint(hi), __float_as_uint(lo), 0x07060302u);
}

__device__ __forceinline__ f32x4 expand2(unsigned u, unsigned v) {
  f32x4 e;
  e.x = __uint_as_float(u << 16);
  e.y = __uint_as_float(u & 0xFFFF0000u);
  e.z = __uint_as_float(v << 16);
  e.w = __uint_as_float(v & 0xFFFF0000u);
  return e;
}

__device__ __forceinline__ f32x4 exp4(f32x4 v) {
  f32x4 r;
  r.x = __expf(v.x);
  r.y = __expf(v.y);
  r.z = __expf(v.z);
  r.w = __expf(v.w);
  return r;
}

__device__ __forceinline__ float exp2i(int d) {  // 2^d for d in [-126, 127]
  return (d <= -127) ? 0.f : __uint_as_float((unsigned)(127 + d) << 23);
}

__device__ __forceinline__ float scr_rd(const char* scr, int scrStride, long F) {
  return *(const float*)(scr + (F >> 5) * (long)scrStride + (F & 31) * 4);
}

// ---------- 32-col step: Q = E*Acc (16 MFMA), Acc' = Q .* e ----------
// ps[nt][mt]: rows mt*16+q4*4.., cols h*32 + nt*16 + col. e fragment
// depends on (mt, q4) only -> shared by both nt chains.
__device__ __forceinline__ void step32(f32x4 (&ps)[2][4], const bf16x8 (&af)[4][2],
                                       const char* lrow) {
  const f32x4 e0 = *(const f32x4*)(lrow + 0);
  const f32x4 e1 = *(const f32x4*)(lrow + 16);
  const f32x4 e2 = *(const f32x4*)(lrow + 32);
  const f32x4 e3 = *(const f32x4*)(lrow + 48);
  const f32x4 z4 = {0.f, 0.f, 0.f, 0.f};
#pragma unroll
  for (int nt = 0; nt < 2; ++nt) {
    union { unsigned u[4]; bf16x8 s; } b0u, b1u;
    b0u.u[0] = pack2bf(ps[nt][0].x, ps[nt][0].y);
    b0u.u[1] = pack2bf(ps[nt][0].z, ps[nt][0].w);
    b0u.u[2] = pack2bf(ps[nt][1].x, ps[nt][1].y);
    b0u.u[3] = pack2bf(ps[nt][1].z, ps[nt][1].w);
    b1u.u[0] = pack2bf(ps[nt][2].x, ps[nt][2].y);
    b1u.u[1] = pack2bf(ps[nt][2].z, ps[nt][2].w);
    b1u.u[2] = pack2bf(ps[nt][3].x, ps[nt][3].y);
    b1u.u[3] = pack2bf(ps[nt][3].z, ps[nt][3].w);
    const bf16x8 b0 = b0u.s, b1 = b1u.s;
    f32x4 q0 = __builtin_amdgcn_mfma_f32_16x16x32_bf16(af[0][0], b0, z4, 0, 0, 0);
    f32x4 q1 = __builtin_amdgcn_mfma_f32_16x16x32_bf16(af[1][0], b0, z4, 0, 0, 0);
    f32x4 q2 = __builtin_amdgcn_mfma_f32_16x16x32_bf16(af[2][0], b0, z4, 0, 0, 0);
    f32x4 q3 = __builtin_amdgcn_mfma_f32_16x16x32_bf16(af[3][0], b0, z4, 0, 0, 0);
    q0 = __builtin_amdgcn_mfma_f32_16x16x32_bf16(af[0][1], b1, q0, 0, 0, 0);
    q1 = __builtin_amdgcn_mfma_f32_16x16x32_bf16(af[1][1], b1, q1, 0, 0, 0);
    q2 = __builtin_amdgcn_mfma_f32_16x16x32_bf16(af[2][1], b1, q2, 0, 0, 0);
    q3 = __builtin_amdgcn_mfma_f32_16x16x32_bf16(af[3][1], b1, q3, 0, 0, 0);
    ps[nt][0] = q0 * e0;
    ps[nt][1] = q1 * e1;
    ps[nt][2] = q2 * e2;
    ps[nt][3] = q3 * e3;
  }
}

// Renorm by exact power of 2 from lane 0's ps[0][0].x exponent.
// Spread bounded (~2^21); 4-step growth <= 2^56 -> max < 2^78, safe.
__device__ __forceinline__ void renorm32(f32x4 (&ps)[2][4], float& tot_e) {
  const unsigned eref = __builtin_amdgcn_readfirstlane(__float_as_uint(ps[0][0].x));
  const int e = (int)((eref >> 23) & 0xFFu) - 127;
  const float sc = __uint_as_float((unsigned)(127 - e) << 23);
#pragma unroll
  for (int nt = 0; nt < 2; ++nt)
#pragma unroll
    for (int mt = 0; mt < 4; ++mt) ps[nt][mt] *= sc;
  tot_e += (float)e;
}

// ---------- chunk kernel: 1 wave = 32 columns of one chunk ----------
__global__ __launch_bounds__(64, 3) void chunk32_kernel(
    const char* __restrict__ un, const float* __restrict__ trans,
    const int* __restrict__ lengths, char* __restrict__ scr, int scrStride) {
  const int bid = blockIdx.x;
  const int b = bid >> 4;
  const int c = (bid >> 1) & 7;
  const int h = bid & 1;  // column half
  const int len = lengths[b];
  const int start = c * kL;
  int steps = len - start;
  if (steps <= 0) return;
  if (steps > kL) steps = kL;

  const int lane = threadIdx.x & 63;
  const int col = lane & 15;
  const int q4 = lane >> 4;

  // Static A-fragments, psi-permuted K (verified rounds 2-11).
  bf16x8 af[4][2];
#pragma unroll
  for (int mt = 0; mt < 4; ++mt) {
#pragma unroll
    for (int kc = 0; kc < 2; ++kc) {
      union { unsigned u[4]; bf16x8 s; } fr;
#pragma unroll
      for (int jp = 0; jp < 4; ++jp) {
        const int j0 = 2 * jp, j1 = 2 * jp + 1;
        const int k0 = (2 * kc + (j0 >> 2)) * 16 + q4 * 4 + (j0 & 3);
        const int k1 = (2 * kc + (j1 >> 2)) * 16 + q4 * 4 + (j1 & 3);
        unsigned e0 = __float_as_uint(__expf(trans[(mt * 16 + col) * kN + k0])) + 0x8000u;
        unsigned e1 = __float_as_uint(__expf(trans[(mt * 16 + col) * kN + k1])) + 0x8000u;
        fr.u[jp] = __builtin_amdgcn_perm(e1, e0, 0x07060302u);
      }
      af[mt][kc] = fr.s;
    }
  }

  // Acc = identity columns h*32 + nt*16 + col.
  f32x4 ps[2][4];
#pragma unroll
  for (int nt = 0; nt < 2; ++nt) {
    const int mycol = h * 32 + nt * 16 + col;
#pragma unroll
    for (int mt = 0; mt < 4; ++mt) {
      const int rb = mt * 16 + q4 * 4;
      f32x4 v;
      v.x = (rb + 0 == mycol) ? 1.f : 0.f;
      v.y = (rb + 1 == mycol) ? 1.f : 0.f;
      v.z = (rb + 2 == mycol) ? 1.f : 0.f;
      v.w = (rb + 3 == mycol) ? 1.f : 0.f;
      ps[nt][mt] = v;
    }
  }

  // Per-wave staging (verbatim r11): 16 raw unary rows per stage, exp +
  // psi-permute en route (psi moves 16B groups as units). No barriers.
  const char* gbase = un + (size_t)(b * kT + start) * 256;
  const int srow = lane >> 2;  // 0..15
  const int sb = lane & 3;     // 0..3
  const size_t gRow = (size_t)srow * 256;

  __shared__ __align__(16) char sm[2][4096];

  {  // preload stage 0
    const char* g = gbase + gRow + sb * 16;
    f32x4 v0 = exp4(*(const f32x4*)(g + 0));
    f32x4 v1 = exp4(*(const f32x4*)(g + 64));
    f32x4 v2 = exp4(*(const f32x4*)(g + 128));
    f32x4 v3 = exp4(*(const f32x4*)(g + 192));
    char* l = &sm[0][0] + gRow + (size_t)sb * 64;
    *(f32x4*)(l + 0) = v0;
    *(f32x4*)(l + 16) = v1;
    *(f32x4*)(l + 32) = v2;
    *(f32x4*)(l + 48) = v3;
  }

  float tot_e = 0.0f;
  const int nst = (steps + 15) >> 4;
  for (int s = 0; s < nst; ++s) {
    f32x4 v0, v1, v2, v3;
    const bool more = (s + 1 < nst);
    if (more) {  // issue next stage's raw loads now; consume after compute
      const char* g = gbase + (size_t)(s + 1) * 4096 + gRow + sb * 16;
      v0 = *(const f32x4*)(g + 0);
      v1 = *(const f32x4*)(g + 64);
      v2 = *(const f32x4*)(g + 128);
      v3 = *(const f32x4*)(g + 192);
    }

    int ns = steps - s * 16;
    ns = ns > 16 ? 16 : ns;
    const char* lb = &sm[s & 1][0] + q4 * 64;
    if (ns == 16) {
      const char* l2 = lb;
#pragma unroll 1
      for (int g4 = 0; g4 < 4; ++g4) {
        step32(ps, af, l2 + 0);
        step32(ps, af, l2 + 256);
        step32(ps, af, l2 + 512);
        step32(ps, af, l2 + 768);
        renorm32(ps, tot_e);
        l2 += 1024;
      }
    } else {
      for (int i = 0; i < ns; ++i) {
        step32(ps, af, lb + (size_t)i * 256);
        if ((i & 3) == 3) renorm32(ps, tot_e);
      }
    }

    if (more) {
      char* l = &sm[(s + 1) & 1][0] + gRow + (size_t)sb * 64;
      *(f32x4*)(l + 0) = exp4(v0);
      *(f32x4*)(l + 16) = exp4(v1);
      *(f32x4*)(l + 32) = exp4(v2);
      *(f32x4*)(l + 48) = exp4(v3);
    }
  }

  // Store 2 x (64x16) tiles, flat F = tile*1024 + col*64 + row -> slots of
  // 32 floats, byte stride scrStride. Per-tile tot_e.
  const long tbase = ((long)b * kC + c) * 4 + h * 2;
#pragma unroll
  for (int nt = 0; nt < 2; ++nt) {
    const long tileIdx = tbase + nt;
#pragma unroll
    for (int mt = 0; mt < 4; ++mt) {
      const long slot = tileIdx * 32 + col * 2 + (mt >> 1);
      char* addr = scr + slot * (long)scrStride + ((mt & 1) * 16 + q4 * 4) * 4;
      *(f32x4*)addr = ps[nt][mt];
    }
    if (lane == 0) {
      const long F = kTileFloats + tileIdx;
      *(float*)(scr + (F >> 5) * (long)scrStride + (F & 31) * 4) = tot_e;
    }
  }
}

// ---------- combine: chain chunk matrices, prefetched ping-pong ----------
__device__ __forceinline__ void load_mat(const char* scr, int scrStride, long tb,
                                         int j, float (&m)[4][16], float (&ev)[4]) {
#pragma unroll
  for (int s = 0; s < 4; ++s) {
#pragma unroll
    for (int k = 0; k < 16; ++k)
      m[s][k] = scr_rd(scr, scrStride, (tb + s) * 1024 + (long)k * 64 + j);
    ev[s] = scr_rd(scr, scrStride, kTileFloats + tb + s);
  }
}

__global__ __launch_bounds__(64, 1) void combine_kernel(
    const char* __restrict__ scr, int scrStride, const float* __restrict__ trans,
    const int* __restrict__ lengths, float* __restrict__ out) {
  const int b = blockIdx.x;
  const int j = threadIdx.x;
  const int len = lengths[b];

  // alpha after chunk 0 = column kStart of chunk-0 matrix.
  const long t0 = (long)b * kC * 4;
  float a = scr_rd(scr, scrStride, t0 * 1024 + kStart * 64 + j);
  float totE = scr_rd(scr, scrStride, kTileFloats + t0);

  float mc[4][16], ec[4];
  load_mat(scr, scrStride, t0 + 4, j, mc, ec);  // chunk 1

#pragma unroll
  for (int c = 1; c < kC; ++c) {
    float mn[4][16], en[4];
    if (c + 1 < kC)  // prefetch chunk c+1 while chaining chunk c
      load_mat(scr, scrStride, t0 + (long)(c + 1) * 4, j, mn, en);

    if (c * kL < len) {  // chunks are contiguous-active
      float s0 = 0.f, s1 = 0.f, s2 = 0.f, s3 = 0.f;
#pragma unroll
      for (int k16 = 0; k16 < 16; ++k16) {
        const float a0 = __int_as_float(__builtin_amdgcn_readlane(__float_as_int(a), k16));
        const float a1 = __int_as_float(__builtin_amdgcn_readlane(__float_as_int(a), 16 + k16));
        const float a2 = __int_as_float(__builtin_amdgcn_readlane(__float_as_int(a), 32 + k16));
        const float a3 = __int_as_float(__builtin_amdgcn_readlane(__float_as_int(a), 48 + k16));
        s0 = fmaf(mc[0][k16], a0, s0);
        s1 = fmaf(mc[1][k16], a1, s1);
        s2 = fmaf(mc[2][k16], a2, s2);
        s3 = fmaf(mc[3][k16], a3, s3);
      }
      const float em = fmaxf(fmaxf(ec[0], ec[1]), fmaxf(ec[2], ec[3]));
      a = s0 * exp2i((int)(ec[0] - em)) + s1 * exp2i((int)(ec[1] - em)) +
          s2 * exp2i((int)(ec[2] - em)) + s3 * exp2i((int)(ec[3] - em));
      totE += em;

      // renorm alpha (exact power of 2 from the wave max)
      float m = a;
#pragma unroll
      for (int mask = 1; mask < 64; mask <<= 1) m = fmaxf(m, __shfl_xor(m, mask));
      const int e = (int)((__float_as_uint(m) >> 23) & 0xFFu) - 127;
      a *= exp2i(-e);
      totE += (float)e;
    }

    if (c + 1 < kC) {  // ping-pong (SSA renames under full unroll)
#pragma unroll
      for (int s = 0; s < 4; ++s) {
#pragma unroll
        for (int k = 0; k < 16; ++k) mc[s][k] = mn[s][k];
        ec[s] = en[s];
      }
    }
  }

  float term = a * __expf(trans[kEnd * kN + j]);
#pragma unroll
  for (int mask = 1; mask < 64; mask <<= 1) term += __shfl_xor(term, mask);

  if (j == 0) out[b] = totE * 0.69314718055994530942f + logf(term);
}

// ================= fallback machinery (ws < scratch): r10/r11 path =========
__global__ void exp_swizzle_bf16(const float* in, char* outbase) {
  const int total = kB * kT * 32;  // pairs
  int p = blockIdx.x * blockDim.x + threadIdx.x;
  const int stride = gridDim.x * blockDim.x;
  for (; p < total; p += stride) {
    const int r = p >> 5;
    const int j0 = (p & 31) << 1;
    const float2 v = *(const float2*)(in + (size_t)r * kN + j0);
    const float e0 = __expf(v.x), e1 = __expf(v.y);
    unsigned u0 = __float_as_uint(e0);
    u0 += 0x7FFFu + ((u0 >> 16) & 1u);  // RNE to bf16
    unsigned u1 = __float_as_uint(e1);
    u1 += 0x7FFFu + ((u1 >> 16) & 1u);
    const unsigned d = (u1 & 0xFFFF0000u) | (u0 >> 16);
    const int pi = ((j0 >> 2) & 3) * 16 + ((j0 >> 4) << 2) + (j0 & 3);
    *(unsigned*)(outbase + (size_t)r * 256 + pi * 2) = d;
  }
}

__device__ __forceinline__ void step_lds_bf16(f32x4 (&ps)[4], const bf16x8 (&af)[4][2],
                                              const char* lrow) {
  const uint4 u0 = *(const uint4*)(lrow + 0);
  const uint4 u1 = *(const uint4*)(lrow + 16);
  f32x4 e0 = expand2(u0.x, u0.y);
  f32x4 e1 = expand2(u0.z, u0.w);
  f32x4 e2 = expand2(u1.x, u1.y);
  f32x4 e3 = expand2(u1.z, u1.w);

  union { unsigned u[4]; bf16x8 s; } b0u, b1u;
  b0u.u[0] = pack2bf(ps[0].x, ps[0].y);
  b0u.u[1] = pack2bf(ps[0].z, ps[0].w);
  b0u.u[2] = pack2bf(ps[1].x, ps[1].y);
  b0u.u[3] = pack2bf(ps[1].z, ps[1].w);
  const bf16x8 b0 = b0u.s;
  const f32x4 z4 = {0.f, 0.f, 0.f, 0.f};
  f32x4 q0 = __builtin_amdgcn_mfma_f32_16x16x32_bf16(af[0][0], b0, z4, 0, 0, 0);
  f32x4 q1 = __builtin_amdgcn_mfma_f32_16x16x32_bf16(af[1][0], b0, z4, 0, 0, 0);
  f32x4 q2 = __builtin_amdgcn_mfma_f32_16x16x32_bf16(af[2][0], b0, z4, 0, 0, 0);
  f32x4 q3 = __builtin_amdgcn_mfma_f32_16x16x32_bf16(af[3][0], b0, z4, 0, 0, 0);
  b1u.u[0] = pack2bf(ps[2].x, ps[2].y);
  b1u.u[1] = pack2bf(ps[2].z, ps[2].w);
  b1u.u[2] = pack2bf(ps[3].x, ps[3].y);
  b1u.u[3] = pack2bf(ps[3].z, ps[3].w);
  const bf16x8 b1 = b1u.s;
  q0 = __builtin_amdgcn_mfma_f32_16x16x32_bf16(af[0][1], b1, q0, 0, 0, 0);
  q1 = __builtin_amdgcn_mfma_f32_16x16x32_bf16(af[1][1], b1, q1, 0, 0, 0);
  q2 = __builtin_amdgcn_mfma_f32_16x16x32_bf16(af[2][1], b1, q2, 0, 0, 0);
  q3 = __builtin_amdgcn_mfma_f32_16x16x32_bf16(af[3][1], b1, q3, 0, 0, 0);

  ps[0] = q0 * e0;
  ps[1] = q1 * e1;
  ps[2] = q2 * e2;
  ps[3] = q3 * e3;
}

__device__ __forceinline__ void renorm16(f32x4 (&ps)[4], float& tot_e) {
  const unsigned eref = __builtin_amdgcn_readfirstlane(__float_as_uint(ps[0].x));
  const int e = (int)((eref >> 23) & 0xFFu) - 127;
  const float sc = __uint_as_float((unsigned)(127 - e) << 23);
#pragma unroll
  for (int mt = 0; mt < 4; ++mt) ps[mt] *= sc;
  tot_e += (float)e;
}

__global__ __launch_bounds__(256, 3) void chunk_pair_bf16_kernel(
    const char* __restrict__ eu, const float* __restrict__ trans,
    const int* __restrict__ lengths, char* __restrict__ scr, int scrStride) {
  constexpr int RB = 128;
  constexpr int SEG = RB / 8;
  constexpr int STG = 32 * RB;

  const int b = blockIdx.x >> 2;
  const int cp = blockIdx.x & 3;
  const int len = lengths[b];
  const int cA = 2 * cp, cB = 2 * cp + 1;
  int stepsA = len - cA * kL;
  stepsA = stepsA < 0 ? 0 : (stepsA > kL ? kL : stepsA);
  int stepsB = len - cB * kL;
  stepsB = stepsB < 0 ? 0 : (stepsB > kL ? kL : stepsB);
  if (stepsA <= 0) return;

  const int t8 = threadIdx.x;
  const int lane = t8 & 63;
  const int w = t8 >> 6;
  const int col = lane & 15;
  const int q4 = lane >> 4;

  bf16x8 af[4][2];
#pragma unroll
  for (int mt = 0; mt < 4; ++mt) {
#pragma unroll
    for (int kc = 0; kc < 2; ++kc) {
      union { unsigned u[4]; bf16x8 s; } fr;
#pragma unroll
      for (int jp = 0; jp < 4; ++jp) {
        const int j0 = 2 * jp, j1 = 2 * jp + 1;
        const int k0 = (2 * kc + (j0 >> 2)) * 16 + q4 * 4 + (j0 & 3);
        const int k1 = (2 * kc + (j1 >> 2)) * 16 + q4 * 4 + (j1 & 3);
        unsigned e0 = __float_as_uint(__expf(trans[(mt * 16 + col) * kN + k0])) + 0x8000u;
        unsigned e1 = __float_as_uint(__expf(trans[(mt * 16 + col) * kN + k1])) + 0x8000u;
        fr.u[jp] = __builtin_amdgcn_perm(e1, e0, 0x07060302u);
      }
      af[mt][kc] = fr.s;
    }
  }

  const int mycol = w * 16 + col;
  f32x4 psA[4], psB[4];
#pragma unroll
  for (int mt = 0; mt < 4; ++mt) {
    const int rb = mt * 16 + q4 * 4;
    f32x4 v;
    v.x = (rb + 0 == mycol) ? 1.f : 0.f;
    v.y = (rb + 1 == mycol) ? 1.f : 0.f;
    v.z = (rb + 2 == mycol) ? 1.f : 0.f;
    v.w = (rb + 3 == mycol) ? 1.f : 0.f;
    psA[mt] = v;
    psB[mt] = v;
  }

  const char* gblkA = eu + (size_t)(b * kT + cA * kL) * 256;
  const char* gblkB = eu + (size_t)(b * kT + cB * kL) * 256;
  const size_t gOff = (size_t)(t8 >> 3) * 256 + (size_t)(t8 & 7) * SEG;
  const size_t lOff = (size_t)(t8 >> 3) * RB + (size_t)(t8 & 7) * SEG;

  __shared__ __align__(16) char smem[2][2][STG];

  {
    uint4 vaA = *(const uint4*)(gblkA + gOff);
    uint4 vaB = *(const uint4*)(gblkB + gOff);
    *(uint4*)(&smem[0][0][0] + lOff) = vaA;
    *(uint4*)(&smem[1][0][0] + lOff) = vaB;
  }
  __syncthreads();

  float totA = 0.0f, totB = 0.0f;
  for (int s = 0; s < 8; ++s) {
    uint4 vaA, vaB;
    const bool more = (s < 7);
    if (more) {
      vaA = *(const uint4*)(gblkA + (size_t)(s + 1) * 8192 + gOff);
      vaB = *(const uint4*)(gblkB + (size_t)(s + 1) * 8192 + gOff);
    }

    int nsA = stepsA - s * 32;
    nsA = nsA < 0 ? 0 : (nsA > 32 ? 32 : nsA);
    int nsB = stepsB - s * 32;
    nsB = nsB < 0 ? 0 : (nsB > 32 ? 32 : nsB);
    const char* lbA = &smem[0][s & 1][0] + q4 * (RB / 4);
    const char* lbB = &smem[1][s & 1][0] + q4 * (RB / 4);

    if (nsA == 32 && nsB == 32) {
      for (int g = 0; g < 8; ++g) {
#pragma unroll
        for (int k = 0; k < 4; ++k) {
          step_lds_bf16(psA, af, lbA + (g * 4 + k) * RB);
          step_lds_bf16(psB, af, lbB + (g * 4 + k) * RB);
        }
        renorm16(psA, totA);
        renorm16(psB, totB);
      }
    } else {
      for (int i = 0; i < nsA; ++i) {
        step_lds_bf16(psA, af, lbA + (size_t)i * RB);
        if ((i & 3) == 3) renorm16(psA, totA);
      }
      for (int i = 0; i < nsB; ++i) {
        step_lds_bf16(psB, af, lbB + (size_t)i * RB);
        if ((i & 3) == 3) renorm16(psB, totB);
      }
    }

    if (more) {
      *(uint4*)(&smem[0][(s + 1) & 1][0] + lOff) = vaA;
      *(uint4*)(&smem[1][(s + 1) & 1][0] + lOff) = vaB;
    }
    __syncthreads();
  }

  {
    const long tileIdx = ((long)b * kC + cA) * 4 + w;
#pragma unroll
    for (int mt = 0; mt < 4; ++mt) {
      const long slot = tileIdx * 32 + col * 2 + (mt >> 1);
      char* addr = scr + slot * (long)scrStride + ((mt & 1) * 16 + q4 * 4) * 4;
      *(f32x4*)addr = psA[mt];
    }
    if (lane == 0) {
      const long F = kTileFloats + tileIdx;
      *(float*)(scr + (F >> 5) * (long)scrStride + (F & 31) * 4) = totA;
    }
  }
  if (stepsB > 0) {
    const long tileIdx = ((long)b * kC + cB) * 4 + w;
#pragma unroll
    for (int mt = 0; mt < 4; ++mt) {
      const long slot = tileIdx * 32 + col * 2 + (mt >> 1);
      char* addr = scr + slot * (long)scrStride + ((mt & 1) * 16 + q4 * 4) * 4;
      *(f32x4*)addr = psB[mt];
    }
    if (lane == 0) {
      const long F = kTileFloats + tileIdx;
      *(float*)(scr + (F >> 5) * (long)scrStride + (F & 31) * 4) = totB;
    }
  }
}

extern "C" void kernel_launch(void* const* d_in, const int* in_sizes, int n_in,
                              void* d_out, int out_size, void* d_ws, size_t ws_size,
                              hipStream_t stream) {
  const float* unary = (const float*)d_in[0];  // [B, T, N] fp32, 128 MiB
  const float* trans = (const float*)d_in[1];  // [N, N] fp32
  const int* lengths = (const int*)d_in[2];    // [B] int32
  float* out = (float*)d_out;                  // [B] fp32

  const size_t scrBytes = (size_t)(kTileFloats + kNumTiles) * 4;  // ~33.6 MB

  if (ws_size >= scrBytes) {
    // Primary: read raw unary directly (exp fused into staging); tiles in
    // workspace; inputs never written.
    chunk32_kernel<<<dim3(kB * kC * 2), dim3(64), 0, stream>>>(
        (const char*)d_in[0], trans, lengths, (char*)d_ws, 128);
    combine_kernel<<<dim3(kB), dim3(64), 0, stream>>>((const char*)d_ws, 128,
                                                      trans, lengths, out);
  } else {
    // Fallback: bf16 eu in lower 128 B of each 256-B row of d_in[0]; tiles
    // in the upper 128 B halves (byte-disjoint; harness restores inputs).
    exp_swizzle_bf16<<<dim3(4096), dim3(256), 0, stream>>>(unary, (char*)d_in[0]);
    chunk_pair_bf16_kernel<<<dim3(kB * 4), dim3(256), 0, stream>>>(
        (const char*)d_in[0], trans, lengths, (char*)d_in[0] + 128, 256);
    combine_kernel<<<dim3(kB), dim3(64), 0, stream>>>((const char*)d_in[0] + 128,
                                                      256, trans, lengths, out);
  }
}